// Round 1
// 206.995 us; speedup vs baseline: 1.3182x; 1.3182x over previous
//
#include <hip/hip_runtime.h>
#include <stdint.h>

// YoloNAS postprocess, fp32 in/out — R9.
// memset | k_conf (2048 blk): conf/argmax -> bins16 + SWIZZLED 32k hist
//        | k_gather (256 blk): per-block redundant cutoff + block-aggregated candidate emit
//        | k_final (1 blk): register bitonic sort (4/thread, shfl) -> prep ->
//          class-grouped suppression bitmasks -> 80-lane register greedy -> output
// R9 changes vs R8 (both pure layout/contention fixes; bin NUMBERS and all fp32
// math identical, absmax must stay 0):
//  (1) hist address swizzle slot(b)=((b&2047)<<4)|(b>>11): value-adjacent hot bins
//      (top ~16 bins each ~320 atomics) no longer share one 64B line -> per-line
//      serialized atomics drop ~5100 -> ~330. Theory: k_conf's 97us at 6% VALUBusy
//      is hot-line atomic serialization.
//  (2) k_gather emits via LDS-aggregated block counter: 256 global atomics on
//      ctrl[0] instead of ~1300 returning atomics to one address.

#define N_ANCH   262144
#define N_CLS    80
#define K_TOP    1024
#define CAP      4096

typedef unsigned long long ull;

// hist layout bijection: bit-rotate 15-bit bin, b = [b14..b11 | b10..b0]
// -> slot = [b10..b0 | b14..b11]. Value-adjacent bins land 16 u32 (64B) apart.
#define HSLOT(b) ((((b) & 2047u) << 4) | ((b) >> 11))

// ---- workspace layout (bytes); total 688192 < proven ws_size >= 733248 ----
#define OFF_HIST  0           // u32[32768] (swizzled layout)
#define OFF_CTRL  131072      // u32[16]: [0]=cand counter, [1]=nsel
#define MEMSET_BYTES 131136
#define OFF_BINS  131136      // u16[262144]: valid?0x8000|bin:0
#define OFF_LIST  655424      // u64[4096] candidate keys
#define WS_REQUIRED 688192

__global__ __launch_bounds__(256) void k_sentinel(float* __restrict__ out, float v) {
    int i = blockIdx.x * 256 + threadIdx.x;
    if (i < K_TOP * 6) out[i] = v;
}

static __device__ __forceinline__ uint32_t conf_key24(float best) {
    uint32_t u = __float_as_uint(best);
    if (u > 0x3F800000u) u = 0x3F800000u;    // defensive; conf in [0.5, 1]
    if (u < 0x3F000000u) u = 0x3F000000u;
    return u - 0x3F000000u;                  // 0..0x800000, monotone in conf
}

static __device__ __forceinline__ void cmpsw(ull& x, ull& y, bool up) {
    ull mn = x < y ? x : y, mx = x < y ? y : x;
    x = up ? mn : mx; y = up ? mx : mn;
}
static __device__ __forceinline__ void cmpswu(uint32_t& x, uint32_t& y, bool up) {
    uint32_t mn = x < y ? x : y, mx = x < y ? y : x;
    x = up ? mn : mx; y = up ? mx : mn;
}

// ---------- kernel 1: conf/argmax, 16 lanes/anchor, 128 anchors/block ----------
__global__ __launch_bounds__(256) void k_conf(const float* __restrict__ scores,
                                              uint16_t* __restrict__ bins16,
                                              uint32_t* __restrict__ hist) {
    const int t = threadIdx.x;
    const int r = t >> 4, s = t & 15;
    const int a0 = blockIdx.x * 128 + r;
    const float* base = scores + (size_t)a0 * N_CLS;
    float4 v0 = ((const float4*)base)[s];
    float4 v1;
    if (s < 4) v1 = ((const float4*)base)[16 + s];
    #pragma unroll
    for (int i = 0; i < 8; i++) {
        float4 c0 = v0, c1 = v1;
        if (i + 1 < 8) {                              // software-pipeline next tile
            const float* nb = base + (size_t)(i + 1) * 16 * N_CLS;
            v0 = ((const float4*)nb)[s];
            if (s < 4) v1 = ((const float4*)nb)[16 + s];
        }
        float best = c0.x; int lab = 4 * s;           // first-max (strict >)
        if (c0.y > best) { best = c0.y; lab = 4 * s + 1; }
        if (c0.z > best) { best = c0.z; lab = 4 * s + 2; }
        if (c0.w > best) { best = c0.w; lab = 4 * s + 3; }
        if (s < 4) {
            const int c = 64 + 4 * s;
            if (c1.x > best) { best = c1.x; lab = c; }
            if (c1.y > best) { best = c1.y; lab = c + 1; }
            if (c1.z > best) { best = c1.z; lab = c + 2; }
            if (c1.w > best) { best = c1.w; lab = c + 3; }
        }
        ull key = ((ull)(uint32_t)__float_as_uint(best) << 7) | (ull)(uint32_t)(127 - lab);
        ull o;
        o = __shfl_xor(key, 1); if (o > key) key = o;
        o = __shfl_xor(key, 2); if (o > key) key = o;
        o = __shfl_xor(key, 4); if (o > key) key = o;
        o = __shfl_xor(key, 8); if (o > key) key = o;
        if (s == 0) {
            const int a = a0 + i * 16;
            float bv = __uint_as_float((uint32_t)(key >> 7));
            uint16_t pk = 0;
            if (bv >= 0.5f) {
                uint32_t bin = conf_key24(bv) >> 8;
                if (bin > 32767u) bin = 32767u;
                atomicAdd(&hist[HSLOT(bin)], 1u);     // swizzled slot, linear bin number
                pk = (uint16_t)(0x8000u | bin);
            }
            bins16[a] = pk;
        }
    }
}

// ---------- kernel 2: per-block redundant cutoff + block-aggregated emit ----------
__global__ __launch_bounds__(256) void k_gather(const float* __restrict__ scores,
                                                const uint16_t* __restrict__ bins16,
                                                const uint32_t* __restrict__ hist,
                                                uint32_t* __restrict__ ctrl,
                                                ull* __restrict__ list) {
    __shared__ uint32_t part[256], suf[256], cbin[2], lcnt, lbase;
    const int t = threadIdx.x, b = blockIdx.x;
    if (t == 0) { lcnt = 0; lbase = 0; }
    // segment sums (128 bins/thread) through the swizzle -> suffix scan -> crossing bin
    {
        // bins for thread t: b15 = t*128 + i, i in [0,128)
        // slot(b15) = ((t&15)<<11) | (i<<4) | (t>>4): stride 16 u32 per i;
        // lanes t, t+16, t+32, ... read consecutive u32s of one 64B line (coalesced).
        const uint32_t sbase = (((uint32_t)t & 15u) << 11) | ((uint32_t)t >> 4);
        uint32_t s = 0;
        for (int i = 0; i < 128; i++) s += hist[sbase + ((uint32_t)i << 4)];
        part[t] = s; suf[t] = s;
    }
    __syncthreads();
    for (int off = 1; off < 256; off <<= 1) {
        uint32_t v = (t + off < 256) ? suf[t + off] : 0;
        __syncthreads();
        suf[t] += v;
        __syncthreads();
    }
    if (t == 0) { cbin[0] = 0; cbin[1] = suf[0]; }
    __syncthreads();
    {
        uint32_t run = suf[t] - part[t];              // count above my segment
        if (run < K_TOP && run + part[t] >= K_TOP) {  // unique crossing segment
            for (int i = 127; i >= 0; i--) {
                uint32_t bi = (uint32_t)(t * 128 + i);
                uint32_t c = hist[HSLOT(bi)];
                if (run < K_TOP && run + c >= K_TOP) { cbin[0] = bi; break; }
                run += c;
            }
        }
    }
    __syncthreads();
    const uint32_t cT = cbin[0];
    if (b == 0 && t == 0) {
        uint32_t total = cbin[1];
        ctrl[1] = (total < K_TOP) ? total : K_TOP;    // nsel
    }
    // scan my 4-anchor slice, re-derive exact keys for hits; collect in registers
    const int a4 = b * 256 + t;
    ushort4 pk4 = ((const ushort4*)bins16)[a4];
    uint16_t pk[4] = {pk4.x, pk4.y, pk4.z, pk4.w};
    ull      hk[4];                                   // keys  (compile-time indexed)
    uint32_t hs[4];                                   // local slots
    bool     hv[4];                                   // valid
    #pragma unroll
    for (int e = 0; e < 4; e++) {
        hv[e] = false; hk[e] = 0; hs[e] = 0;
        uint32_t u = pk[e];
        if ((u & 0x8000u) && (u & 0x7FFFu) >= cT) {
            const uint32_t a = (uint32_t)a4 * 4u + (uint32_t)e;
            const float4* row = (const float4*)(scores + (size_t)a * N_CLS);
            float best = -1.f; int lab = 0;
            for (int f = 0; f < 20; f++) {
                float4 w = row[f];
                if (w.x > best) { best = w.x; lab = 4 * f; }
                if (w.y > best) { best = w.y; lab = 4 * f + 1; }
                if (w.z > best) { best = w.z; lab = 4 * f + 2; }
                if (w.w > best) { best = w.w; lab = 4 * f + 3; }
            }
            if (best >= 0.5f) {
                uint32_t k24 = conf_key24(best);
                hk[e] = ((ull)(0x1000000u - k24) << 25) | ((ull)a << 7)
                      | (ull)(uint32_t)lab;           // ascending = conf desc, idx asc
                hs[e] = atomicAdd(&lcnt, 1u);         // LDS: ~5 hits/block, no contention
                hv[e] = true;
            }
        }
    }
    __syncthreads();
    if (t == 0 && lcnt) lbase = atomicAdd(&ctrl[0], lcnt);  // ONE global atomic/block
    __syncthreads();
    const uint32_t base2 = lbase;
    #pragma unroll
    for (int e = 0; e < 4; e++) {
        if (hv[e]) {
            uint32_t slot = base2 + hs[e];
            if (slot < CAP) list[slot] = hk[e];       // list order irrelevant: k_final sorts
        }
    }
}

// ---------- kernel 3: sort + prep + class-bitmask NMS + output (1 block) ----------
// LDS: sort scratch sk u64[4096]@0 (32KB, dead after extract); then
// ob f4[1024]@0 | ar f[1024]@16384 | red16 f[16]@20480 | g u32[1024]@20544 |
// sup u64[1024]@24640 | keepA u8[1024]@32832 | cnt u32[80]@33856 | stt u32[80]@34176 |
// ovr u8[80]@34496
__global__ __launch_bounds__(1024) void k_final(const float4* __restrict__ bboxes,
                                                const uint32_t* __restrict__ ctrl,
                                                const ull* __restrict__ list,
                                                float* __restrict__ out) {
    __shared__ __align__(16) char smem[34624];
    ull*      sk    = (ull*)smem;
    float4*   ob    = (float4*)smem;
    float*    ar    = (float*)(smem + 16384);
    float*    red16 = (float*)(smem + 20480);
    uint32_t* g     = (uint32_t*)(smem + 20544);
    ull*      sup   = (ull*)(smem + 24640);
    uint8_t*  keepA = (uint8_t*)(smem + 32832);
    uint32_t* cnt   = (uint32_t*)(smem + 33856);
    uint32_t* stt   = (uint32_t*)(smem + 34176);
    uint8_t*  ovr   = (uint8_t*)(smem + 34496);
    const int t = threadIdx.x;
    const uint32_t nsel = ctrl[1];
    uint32_t ncand = ctrl[0]; if (ncand > CAP) ncand = CAP;

    // ---- register bitonic sort: 4096 elements, 4/thread; LDS only when j>=256 ----
    ull E[4];
    #pragma unroll
    for (int rr = 0; rr < 4; rr++) {
        int e = 4 * t + rr;
        E[rr] = (e < (int)ncand) ? list[e] : ~0ull;
    }
    for (int k = 2; k <= CAP; k <<= 1) {
        for (int j = k >> 1; j > 0; j >>= 1) {
            if (j >= 256) {                           // cross-wave: LDS pass
                __syncthreads();
                #pragma unroll
                for (int rr = 0; rr < 4; rr++) sk[4 * t + rr] = E[rr];
                __syncthreads();
                #pragma unroll
                for (int rr = 0; rr < 4; rr++) {
                    int e = 4 * t + rr;
                    ull o = sk[e ^ j];
                    bool keepMax = (((e & k) == 0) != ((e & j) == 0));
                    bool gt = E[rr] > o;
                    E[rr] = (gt == keepMax) ? E[rr] : o;
                }
            } else if (j >= 4) {                      // in-wave: shfl_xor
                int d = j >> 2;
                #pragma unroll
                for (int rr = 0; rr < 4; rr++) {
                    int e = 4 * t + rr;
                    ull o = __shfl_xor(E[rr], d);
                    bool keepMax = (((e & k) == 0) != ((e & j) == 0));
                    bool gt = E[rr] > o;
                    E[rr] = (gt == keepMax) ? E[rr] : o;
                }
            } else if (j == 2) {                      // in-thread
                bool up = (((4 * t) & k) == 0);
                cmpsw(E[0], E[2], up); cmpsw(E[1], E[3], up);
            } else {
                bool upA = (((4 * t) & k) == 0);
                bool upB = (((4 * t + 2) & k) == 0);
                cmpsw(E[0], E[1], upA); cmsw_dummy:;
                cmpsw(E[2], E[3], upB);
            }
        }
    }
    __syncthreads();
    #pragma unroll
    for (int rr = 0; rr < 4; rr++) sk[4 * t + rr] = E[rr];
    __syncthreads();
    ull skey = sk[t];                                 // rank t
    __syncthreads();                                  // sk region free for reuse

    // ---- extract + gather + prep (exact reference fp32 order; max is associative) ----
    float4 bx = make_float4(0.f, 0.f, 0.f, 0.f);
    float cf = 0.f, lb = 0.f;
    uint32_t lab = 0;
    if ((uint32_t)t < nsel) {
        uint32_t idx = (uint32_t)(skey >> 7) & 0x3FFFFu;
        lab = (uint32_t)skey & 127u;
        cf = __uint_as_float(0x3F000000u + (0x1000000u - (uint32_t)(skey >> 25)));
        lb = (float)lab;
        bx = bboxes[idx];
    }
    float m = fmaxf(fmaxf(bx.x, bx.y), fmaxf(bx.z, bx.w));
    for (int d = 32; d > 0; d >>= 1) m = fmaxf(m, __shfl_xor(m, d));
    if ((t & 63) == 0) red16[t >> 6] = m;
    __syncthreads();
    float M = red16[0];
    #pragma unroll
    for (int w = 1; w < 16; w++) M = fmaxf(M, red16[w]);
    M = __fadd_rn(M, 1.0f);
    float o = __fmul_rn(lb, M);
    float4 q;
    q.x = __fadd_rn(bx.x, o); q.y = __fadd_rn(bx.y, o);
    q.z = __fadd_rn(bx.z, o); q.w = __fadd_rn(bx.w, o);
    ob[t] = q;
    ar[t] = __fmul_rn(__fsub_rn(q.z, q.x), __fsub_rn(q.w, q.y));
    g[t] = ((uint32_t)t < nsel) ? ((lab << 10) | (uint32_t)t) : 0xFFFFFFFFu;
    if (t < N_CLS) { cnt[t] = 0; ovr[t] = 0; stt[t] = 0; }
    keepA[t] = 0;
    __syncthreads();

    // ---- class-group sort: 1024 u32 keys (lab<<10|rank), 4/thread on t<256 ----
    uint32_t G[4];
    if (t < 256) {
        #pragma unroll
        for (int rr = 0; rr < 4; rr++) G[rr] = g[4 * t + rr];
    }
    for (int k = 2; k <= 1024; k <<= 1) {
        for (int j = k >> 1; j > 0; j >>= 1) {
            if (j >= 256) {
                __syncthreads();
                if (t < 256) {
                    #pragma unroll
                    for (int rr = 0; rr < 4; rr++) g[4 * t + rr] = G[rr];
                }
                __syncthreads();
                if (t < 256) {
                    #pragma unroll
                    for (int rr = 0; rr < 4; rr++) {
                        int e = 4 * t + rr;
                        uint32_t o2 = g[e ^ j];
                        bool keepMax = (((e & k) == 0) != ((e & j) == 0));
                        bool gt = G[rr] > o2;
                        G[rr] = (gt == keepMax) ? G[rr] : o2;
                    }
                }
            } else if (t < 256) {
                if (j >= 4) {
                    int d = j >> 2;
                    #pragma unroll
                    for (int rr = 0; rr < 4; rr++) {
                        int e = 4 * t + rr;
                        uint32_t o2 = (uint32_t)__shfl_xor((int)G[rr], d);
                        bool keepMax = (((e & k) == 0) != ((e & j) == 0));
                        bool gt = G[rr] > o2;
                        G[rr] = (gt == keepMax) ? G[rr] : o2;
                    }
                } else if (j == 2) {
                    bool up = (((4 * t) & k) == 0);
                    cmpswu(G[0], G[2], up); cmpswu(G[1], G[3], up);
                } else {
                    bool upA = (((4 * t) & k) == 0);
                    bool upB = (((4 * t + 2) & k) == 0);
                    cmpswu(G[0], G[1], upA); cmpswu(G[2], G[3], upB);
                }
            }
        }
    }
    __syncthreads();
    if (t < 256) {
        #pragma unroll
        for (int rr = 0; rr < 4; rr++) g[4 * t + rr] = G[rr];
    }
    __syncthreads();

    // ---- class boundaries + counts ----
    uint32_t gp = g[t];
    if (gp != 0xFFFFFFFFu) {
        uint32_t labp = gp >> 10;
        atomicAdd(&cnt[labp], 1u);
        if (t == 0 || (g[t - 1] >> 10) != labp) stt[labp] = (uint32_t)t;
    }
    __syncthreads();

    // ---- parallel suppression bitmask: sup[p] bit (q-p-1) = iou(p,q)>thr, same class ----
    {
        ull sp = 0;
        if (gp != 0xFFFFFFFFu) {
            uint32_t labi = gp >> 10;
            uint32_t ri = gp & 1023u;
            float4 oi = ob[ri]; float ai = ar[ri];
            for (int qq = t + 1; qq < 1024; qq++) {
                uint32_t gq = g[qq];
                if ((gq >> 10) != labi) break;
                int dq = qq - t;
                if (dq > 64) { ovr[labi] = 1; break; }
                uint32_t rj = gq & 1023u;
                float4 oj = ob[rj];
                float lx = fmaxf(oi.x, oj.x), ly = fmaxf(oi.y, oj.y);
                float rx = fminf(oi.z, oj.z), ry = fminf(oi.w, oj.w);
                float wx = fmaxf(__fsub_rn(rx, lx), 0.f);
                float wy = fmaxf(__fsub_rn(ry, ly), 0.f);
                float inter = __fmul_rn(wx, wy);
                float uni = __fsub_rn(__fadd_rn(ai, ar[rj]), inter);
                float iou = __fdiv_rn(inter, fmaxf(uni, 1e-9f));
                if (iou > 0.6f) sp |= 1ull << (dq - 1);
            }
        }
        sup[t] = sp;
    }
    __syncthreads();

    // ---- 80-lane register greedy (rank order within class = score order) ----
    if (t < N_CLS) {
        uint32_t n = cnt[t];
        if (n > 0) {
            uint32_t s0 = stt[t];
            if (n <= 64 && !ovr[t]) {
                ull kill = 0;
                for (uint32_t i = 0; i < n; i++) {
                    if (!((kill >> i) & 1ull)) {
                        if (i + 1 < 64) kill |= sup[s0 + i] << (i + 1);
                        keepA[g[s0 + i] & 1023u] = 1;
                    }
                }
            } else {                                  // oversized class: serial fallback
                for (uint32_t i = 0; i < n; i++) {
                    uint32_t ri = g[s0 + i] & 1023u;
                    float4 oi = ob[ri]; float ai = ar[ri];
                    bool kp = true;
                    for (uint32_t m2 = 0; m2 < i && kp; m2++) {
                        uint32_t rm = g[s0 + m2] & 1023u;
                        if (!keepA[rm]) continue;
                        float4 om = ob[rm];
                        float lx = fmaxf(om.x, oi.x), ly = fmaxf(om.y, oi.y);
                        float rx = fminf(om.z, oi.z), ry = fminf(om.w, oi.w);
                        float wx = fmaxf(__fsub_rn(rx, lx), 0.f);
                        float wy = fmaxf(__fsub_rn(ry, ly), 0.f);
                        float inter = __fmul_rn(wx, wy);
                        float uni = __fsub_rn(__fadd_rn(ar[rm], ai), inter);
                        float iou = __fdiv_rn(inter, fmaxf(uni, 1e-9f));
                        if (iou > 0.6f) kp = false;
                    }
                    keepA[ri] = kp ? 1 : 0;
                }
            }
        }
    }
    __syncthreads();

    // ---- masked fp32 output ----
    const bool keep = keepA[t] != 0;
    float v0 = keep ? bx.x : 0.f, v1 = keep ? bx.y : 0.f;
    float v2 = keep ? bx.z : 0.f, v3 = keep ? bx.w : 0.f;
    float v4 = keep ? cf : 0.f, v5 = keep ? lb : 0.f;
    float2* o2 = (float2*)out;
    o2[t * 3 + 0] = make_float2(v0, v1);
    o2[t * 3 + 1] = make_float2(v2, v3);
    o2[t * 3 + 2] = make_float2(v4, v5);
}

extern "C" void kernel_launch(void* const* d_in, const int* in_sizes, int n_in,
                              void* d_out, int out_size, void* d_ws, size_t ws_size,
                              hipStream_t stream) {
    const float* bboxes = (const float*)d_in[0];
    const float* scores = (const float*)d_in[1];
    if (n_in >= 2 && in_sizes[0] > in_sizes[1]) {   // defensive: scores is the 20x larger input
        bboxes = (const float*)d_in[1];
        scores = (const float*)d_in[0];
    }

    if (ws_size < (size_t)WS_REQUIRED) {
        k_sentinel<<<(K_TOP * 6 + 255) / 256, 256, 0, stream>>>(
            (float*)d_out, (float)(ws_size >> 10));
        return;
    }

    char* ws = (char*)d_ws;
    uint32_t* hist   = (uint32_t*)(ws + OFF_HIST);
    uint32_t* ctrl   = (uint32_t*)(ws + OFF_CTRL);
    uint16_t* bins16 = (uint16_t*)(ws + OFF_BINS);
    ull*      list   = (ull*)(ws + OFF_LIST);

    hipMemsetAsync(ws, 0, MEMSET_BYTES, stream);    // hist + ctrl
    k_conf  <<<N_ANCH / 128, 256, 0, stream>>>(scores, bins16, hist);
    k_gather<<<256,          256, 0, stream>>>(scores, bins16, hist, ctrl, list);
    k_final <<<1,           1024, 0, stream>>>((const float4*)bboxes, ctrl, list,
                                               (float*)d_out);
}

// Round 2
// 198.953 us; speedup vs baseline: 1.3715x; 1.0404x over previous
//
#include <hip/hip_runtime.h>
#include <stdint.h>

// YoloNAS postprocess, fp32 in/out — R10.
// memset | k_conf (2048 blk): conf/argmax -> bins16 + SWIZZLED 32k hist
//        | k_cut  (1 blk): cutoff bin + nsel computed ONCE (regs-held bins, shfl scan)
//        | k_gather (256 blk): candidate emit only (reads ctrl[2]=cT)
//        | k_final (1 blk): ADAPTIVE register bitonic (nsort=pow2(ncand), typ. 2048),
//          SKEWED LDS scratch (conflict-free b64 passes) -> prep -> class-grouped
//          suppression bitmasks -> 80-lane register greedy -> output
// R10 changes vs R9 (candidate predicate, sort keys, fp32 NMS math identical; absmax 0):
//  (1) k_cut: the per-block redundant cutoff (strided hist sums + 16-sync scan +
//      SERIAL 128-load crossing search ~12us) ran in all 256 k_gather blocks;
//      now once, with bins held in registers (crossing scan has no reloads).
//  (2) k_final adaptive sort size: ncand ~1100-1400 -> sort 2048 not 4096
//      (stages 78->66, LDS passes 10->6 at half width).
//  (3) k_final sk skew phys(e)=e+(e>>4): unskewed bank-pair=(8t+2rr)%32 = 16
//      lanes/bank-pair (4x min); skew spreads to 4/bank-pair = conflict-free.
//      All j>=256 have (j>>4)%16==0 so reads inherit the spread. Predicts
//      SQ_LDS_BANK_CONFLICT 9128 -> <2000.

#define N_ANCH   262144
#define N_CLS    80
#define K_TOP    1024
#define CAP      4096

typedef unsigned long long ull;

// hist layout bijection: bit-rotate 15-bit bin, b = [b14..b11 | b10..b0]
// -> slot = [b10..b0 | b14..b11]. Value-adjacent bins land 16 u32 (64B) apart.
#define HSLOT(b) ((((b) & 2047u) << 4) | ((b) >> 11))
// skewed LDS index for the u64 sort scratch (conflict-free, see header)
#define SKEW(e) ((uint32_t)(e) + ((uint32_t)(e) >> 4))

// ---- workspace layout (bytes); total 688192 < proven ws_size >= 733248 ----
#define OFF_HIST  0           // u32[32768] (swizzled layout)
#define OFF_CTRL  131072      // u32[16]: [0]=cand counter, [1]=nsel, [2]=cutoff bin
#define MEMSET_BYTES 131136
#define OFF_BINS  131136      // u16[262144]: valid?0x8000|bin:0
#define OFF_LIST  655424      // u64[4096] candidate keys
#define WS_REQUIRED 688192

__global__ __launch_bounds__(256) void k_sentinel(float* __restrict__ out, float v) {
    int i = blockIdx.x * 256 + threadIdx.x;
    if (i < K_TOP * 6) out[i] = v;
}

static __device__ __forceinline__ uint32_t conf_key24(float best) {
    uint32_t u = __float_as_uint(best);
    if (u > 0x3F800000u) u = 0x3F800000u;    // defensive; conf in [0.5, 1]
    if (u < 0x3F000000u) u = 0x3F000000u;
    return u - 0x3F000000u;                  // 0..0x800000, monotone in conf
}

static __device__ __forceinline__ void cmpsw(ull& x, ull& y, bool up) {
    ull mn = x < y ? x : y, mx = x < y ? y : x;
    x = up ? mn : mx; y = up ? mx : mn;
}
static __device__ __forceinline__ void cmpswu(uint32_t& x, uint32_t& y, bool up) {
    uint32_t mn = x < y ? x : y, mx = x < y ? y : x;
    x = up ? mn : mx; y = up ? mx : mn;
}

// ---------- kernel 1: conf/argmax, 16 lanes/anchor, 128 anchors/block ----------
__global__ __launch_bounds__(256) void k_conf(const float* __restrict__ scores,
                                              uint16_t* __restrict__ bins16,
                                              uint32_t* __restrict__ hist) {
    const int t = threadIdx.x;
    const int r = t >> 4, s = t & 15;
    const int a0 = blockIdx.x * 128 + r;
    const float* base = scores + (size_t)a0 * N_CLS;
    float4 v0 = ((const float4*)base)[s];
    float4 v1;
    if (s < 4) v1 = ((const float4*)base)[16 + s];
    #pragma unroll
    for (int i = 0; i < 8; i++) {
        float4 c0 = v0, c1 = v1;
        if (i + 1 < 8) {                              // software-pipeline next tile
            const float* nb = base + (size_t)(i + 1) * 16 * N_CLS;
            v0 = ((const float4*)nb)[s];
            if (s < 4) v1 = ((const float4*)nb)[16 + s];
        }
        float best = c0.x; int lab = 4 * s;           // first-max (strict >)
        if (c0.y > best) { best = c0.y; lab = 4 * s + 1; }
        if (c0.z > best) { best = c0.z; lab = 4 * s + 2; }
        if (c0.w > best) { best = c0.w; lab = 4 * s + 3; }
        if (s < 4) {
            const int c = 64 + 4 * s;
            if (c1.x > best) { best = c1.x; lab = c; }
            if (c1.y > best) { best = c1.y; lab = c + 1; }
            if (c1.z > best) { best = c1.z; lab = c + 2; }
            if (c1.w > best) { best = c1.w; lab = c + 3; }
        }
        ull key = ((ull)(uint32_t)__float_as_uint(best) << 7) | (ull)(uint32_t)(127 - lab);
        ull o;
        o = __shfl_xor(key, 1); if (o > key) key = o;
        o = __shfl_xor(key, 2); if (o > key) key = o;
        o = __shfl_xor(key, 4); if (o > key) key = o;
        o = __shfl_xor(key, 8); if (o > key) key = o;
        if (s == 0) {
            const int a = a0 + i * 16;
            float bv = __uint_as_float((uint32_t)(key >> 7));
            uint16_t pk = 0;
            if (bv >= 0.5f) {
                uint32_t bin = conf_key24(bv) >> 8;
                if (bin > 32767u) bin = 32767u;
                atomicAdd(&hist[HSLOT(bin)], 1u);     // swizzled slot, linear bin number
                pk = (uint16_t)(0x8000u | bin);
            }
            bins16[a] = pk;
        }
    }
}

// ---------- kernel 2: cutoff bin + nsel, once (1 block, 1024 threads) ----------
// Thread t owns bins [32t, 32t+32), held in registers. Wave-level shfl suffix
// scan + 16-wave combine; the unique crossing thread scans its 32 register
// values descending (no reloads, no serial L2 chain).
__global__ __launch_bounds__(1024) void k_cut(const uint32_t* __restrict__ hist,
                                              uint32_t* __restrict__ ctrl) {
    __shared__ uint32_t wtot[16], wsuf[16];
    const int t = threadIdx.x;
    const int lane = t & 63, w = t >> 6;
    // bins b = 32t + i: b>>11 = t>>6 (const), b&2047 = 32(t&63)+i
    // slot = ((t&63)<<9) | (i<<4) | (t>>6)
    const uint32_t sbase = (((uint32_t)t & 63u) << 9) | ((uint32_t)t >> 6);
    uint32_t c[32];
    #pragma unroll
    for (int i = 0; i < 32; i++) c[i] = hist[sbase | ((uint32_t)i << 4)];
    uint32_t part = 0;
    #pragma unroll
    for (int i = 0; i < 32; i++) part += c[i];
    // wave inclusive suffix scan: x = sum of part over lanes >= lane (this wave)
    uint32_t x = part;
    #pragma unroll
    for (int d = 1; d < 64; d <<= 1) {
        uint32_t o = __shfl_down(x, d);
        if (lane + d < 64) x += o;
    }
    if (lane == 0) wtot[w] = x;                       // wave total
    __syncthreads();
    if (t < 16) {
        uint32_t s = 0;
        for (int ww = t + 1; ww < 16; ww++) s += wtot[ww];
        wsuf[t] = s;                                  // waves strictly above
        if (t == 0) {
            uint32_t total = s + wtot[0];
            ctrl[1] = (total < K_TOP) ? total : K_TOP;   // nsel
        }
    }
    __syncthreads();
    uint32_t run = (x + wsuf[w]) - part;              // count strictly above my segment
    if (run < K_TOP && run + part >= K_TOP) {         // unique crossing thread
        uint32_t fnd = 0, cbv = 0;
        #pragma unroll
        for (int i = 31; i >= 0; i--) {               // descending bins, register scan
            if (!fnd && run + c[i] >= K_TOP) { cbv = (uint32_t)(t * 32 + i); fnd = 1; }
            if (!fnd) run += c[i];
        }
        ctrl[2] = cbv;                                // cutoff bin (cT)
    }
    // total < K_TOP: no writer; ctrl[2] stays 0 from memset -> include everything
}

// ---------- kernel 3: candidate emit only ----------
__global__ __launch_bounds__(256) void k_gather(const float* __restrict__ scores,
                                                const uint16_t* __restrict__ bins16,
                                                uint32_t* __restrict__ ctrl,
                                                ull* __restrict__ list) {
    __shared__ uint32_t lcnt, lbase;
    const int t = threadIdx.x, b = blockIdx.x;
    if (t == 0) { lcnt = 0; lbase = 0; }
    __syncthreads();
    const uint32_t cT = ctrl[2];
    // scan my 4-anchor slice, re-derive exact keys for hits; collect in registers
    const int a4 = b * 256 + t;
    ushort4 pk4 = ((const ushort4*)bins16)[a4];
    uint16_t pk[4] = {pk4.x, pk4.y, pk4.z, pk4.w};
    ull      hk[4];                                   // keys  (compile-time indexed)
    uint32_t hs[4];                                   // local slots
    bool     hv[4];                                   // valid
    #pragma unroll
    for (int e = 0; e < 4; e++) {
        hv[e] = false; hk[e] = 0; hs[e] = 0;
        uint32_t u = pk[e];
        if ((u & 0x8000u) && (u & 0x7FFFu) >= cT) {
            const uint32_t a = (uint32_t)a4 * 4u + (uint32_t)e;
            const float4* row = (const float4*)(scores + (size_t)a * N_CLS);
            float best = -1.f; int lab = 0;
            for (int f = 0; f < 20; f++) {
                float4 w = row[f];
                if (w.x > best) { best = w.x; lab = 4 * f; }
                if (w.y > best) { best = w.y; lab = 4 * f + 1; }
                if (w.z > best) { best = w.z; lab = 4 * f + 2; }
                if (w.w > best) { best = w.w; lab = 4 * f + 3; }
            }
            if (best >= 0.5f) {
                uint32_t k24 = conf_key24(best);
                hk[e] = ((ull)(0x1000000u - k24) << 25) | ((ull)a << 7)
                      | (ull)(uint32_t)lab;           // ascending = conf desc, idx asc
                hs[e] = atomicAdd(&lcnt, 1u);         // LDS: ~5 hits/block
                hv[e] = true;
            }
        }
    }
    __syncthreads();
    if (t == 0 && lcnt) lbase = atomicAdd(&ctrl[0], lcnt);  // ONE global atomic/block
    __syncthreads();
    const uint32_t base2 = lbase;
    #pragma unroll
    for (int e = 0; e < 4; e++) {
        if (hv[e]) {
            uint32_t slot = base2 + hs[e];
            if (slot < CAP) list[slot] = hk[e];       // list order irrelevant: k_final sorts
        }
    }
}

// ---------- kernel 4: sort + prep + class-bitmask NMS + output (1 block) ----------
// LDS: sort scratch sk u64[4352 skewed]@0 (34816B, dead after extract); then
// ob f4[1024]@0 | ar f[1024]@16384 | red16 f[16]@20480 | g u32[1024]@20544 |
// sup u64[1024]@24640 | keepA u8[1024]@32832 | cnt u32[80]@33856 | stt u32[80]@34176 |
// ovr u8[80]@34496
__global__ __launch_bounds__(1024) void k_final(const float4* __restrict__ bboxes,
                                                const uint32_t* __restrict__ ctrl,
                                                const ull* __restrict__ list,
                                                float* __restrict__ out) {
    __shared__ __align__(16) char smem[34816];
    ull*      sk    = (ull*)smem;
    float4*   ob    = (float4*)smem;
    float*    ar    = (float*)(smem + 16384);
    float*    red16 = (float*)(smem + 20480);
    uint32_t* g     = (uint32_t*)(smem + 20544);
    ull*      sup   = (ull*)(smem + 24640);
    uint8_t*  keepA = (uint8_t*)(smem + 32832);
    uint32_t* cnt   = (uint32_t*)(smem + 33856);
    uint32_t* stt   = (uint32_t*)(smem + 34176);
    uint8_t*  ovr   = (uint8_t*)(smem + 34496);
    const int t = threadIdx.x;
    const uint32_t nsel = ctrl[1];
    uint32_t ncand = ctrl[0]; if (ncand > CAP) ncand = CAP;

    // ---- adaptive register bitonic: nsort = pow2 >= ncand (>=1024), 4/thread ----
    uint32_t nsort = 1024;
    while (nsort < ncand) nsort <<= 1;                // 1024 / 2048 / 4096 (uniform)
    const int TS = (int)(nsort >> 2);                 // participating threads
    ull E[4];
    if (t < TS) {
        #pragma unroll
        for (int rr = 0; rr < 4; rr++) {
            int e = 4 * t + rr;
            E[rr] = (e < (int)ncand) ? list[e] : ~0ull;
        }
    }
    for (uint32_t k = 2; k <= nsort; k <<= 1) {
        for (uint32_t j = k >> 1; j > 0; j >>= 1) {
            if (j >= 256) {                           // cross-wave: LDS pass (skewed)
                __syncthreads();
                if (t < TS) {
                    #pragma unroll
                    for (int rr = 0; rr < 4; rr++) sk[SKEW(4 * t + rr)] = E[rr];
                }
                __syncthreads();
                if (t < TS) {
                    #pragma unroll
                    for (int rr = 0; rr < 4; rr++) {
                        uint32_t e = 4 * t + rr;
                        ull o = sk[SKEW(e ^ j)];
                        bool keepMax = (((e & k) == 0) != ((e & j) == 0));
                        bool gt = E[rr] > o;
                        E[rr] = (gt == keepMax) ? E[rr] : o;
                    }
                }
            } else if (t < TS) {
                if (j >= 4) {                         // in-wave: shfl_xor (d<=32)
                    int d = (int)(j >> 2);
                    #pragma unroll
                    for (int rr = 0; rr < 4; rr++) {
                        uint32_t e = 4 * t + rr;
                        ull o = __shfl_xor(E[rr], d);
                        bool keepMax = (((e & k) == 0) != ((e & j) == 0));
                        bool gt = E[rr] > o;
                        E[rr] = (gt == keepMax) ? E[rr] : o;
                    }
                } else if (j == 2) {                  // in-thread
                    bool up = (((4 * t) & k) == 0);
                    cmpsw(E[0], E[2], up); cmpsw(E[1], E[3], up);
                } else {
                    bool upA = (((4 * t) & k) == 0);
                    bool upB = (((4 * t + 2) & k) == 0);
                    cmpsw(E[0], E[1], upA);
                    cmpsw(E[2], E[3], upB);
                }
            }
        }
    }
    __syncthreads();
    if (t < TS) {
        #pragma unroll
        for (int rr = 0; rr < 4; rr++) sk[SKEW(4 * t + rr)] = E[rr];
    }
    __syncthreads();
    ull skey = sk[SKEW(t)];                           // rank t (t < 1024 <= nsort)
    __syncthreads();                                  // sk region free for reuse

    // ---- extract + gather + prep (exact reference fp32 order; max is associative) ----
    float4 bx = make_float4(0.f, 0.f, 0.f, 0.f);
    float cf = 0.f, lb = 0.f;
    uint32_t lab = 0;
    if ((uint32_t)t < nsel) {
        uint32_t idx = (uint32_t)(skey >> 7) & 0x3FFFFu;
        lab = (uint32_t)skey & 127u;
        cf = __uint_as_float(0x3F000000u + (0x1000000u - (uint32_t)(skey >> 25)));
        lb = (float)lab;
        bx = bboxes[idx];
    }
    float m = fmaxf(fmaxf(bx.x, bx.y), fmaxf(bx.z, bx.w));
    for (int d = 32; d > 0; d >>= 1) m = fmaxf(m, __shfl_xor(m, d));
    if ((t & 63) == 0) red16[t >> 6] = m;
    __syncthreads();
    float M = red16[0];
    #pragma unroll
    for (int w = 1; w < 16; w++) M = fmaxf(M, red16[w]);
    M = __fadd_rn(M, 1.0f);
    float o = __fmul_rn(lb, M);
    float4 q;
    q.x = __fadd_rn(bx.x, o); q.y = __fadd_rn(bx.y, o);
    q.z = __fadd_rn(bx.z, o); q.w = __fadd_rn(bx.w, o);
    ob[t] = q;
    ar[t] = __fmul_rn(__fsub_rn(q.z, q.x), __fsub_rn(q.w, q.y));
    g[t] = ((uint32_t)t < nsel) ? ((lab << 10) | (uint32_t)t) : 0xFFFFFFFFu;
    if (t < N_CLS) { cnt[t] = 0; ovr[t] = 0; stt[t] = 0; }
    keepA[t] = 0;
    __syncthreads();

    // ---- class-group sort: 1024 u32 keys (lab<<10|rank), 4/thread on t<256 ----
    uint32_t G[4];
    if (t < 256) {
        #pragma unroll
        for (int rr = 0; rr < 4; rr++) G[rr] = g[4 * t + rr];
    }
    for (int k = 2; k <= 1024; k <<= 1) {
        for (int j = k >> 1; j > 0; j >>= 1) {
            if (j >= 256) {
                __syncthreads();
                if (t < 256) {
                    #pragma unroll
                    for (int rr = 0; rr < 4; rr++) g[4 * t + rr] = G[rr];
                }
                __syncthreads();
                if (t < 256) {
                    #pragma unroll
                    for (int rr = 0; rr < 4; rr++) {
                        int e = 4 * t + rr;
                        uint32_t o2 = g[e ^ j];
                        bool keepMax = (((e & k) == 0) != ((e & j) == 0));
                        bool gt = G[rr] > o2;
                        G[rr] = (gt == keepMax) ? G[rr] : o2;
                    }
                }
            } else if (t < 256) {
                if (j >= 4) {
                    int d = j >> 2;
                    #pragma unroll
                    for (int rr = 0; rr < 4; rr++) {
                        int e = 4 * t + rr;
                        uint32_t o2 = (uint32_t)__shfl_xor((int)G[rr], d);
                        bool keepMax = (((e & k) == 0) != ((e & j) == 0));
                        bool gt = G[rr] > o2;
                        G[rr] = (gt == keepMax) ? G[rr] : o2;
                    }
                } else if (j == 2) {
                    bool up = (((4 * t) & k) == 0);
                    cmpswu(G[0], G[2], up); cmpswu(G[1], G[3], up);
                } else {
                    bool upA = (((4 * t) & k) == 0);
                    bool upB = (((4 * t + 2) & k) == 0);
                    cmpswu(G[0], G[1], upA); cmpswu(G[2], G[3], upB);
                }
            }
        }
    }
    __syncthreads();
    if (t < 256) {
        #pragma unroll
        for (int rr = 0; rr < 4; rr++) g[4 * t + rr] = G[rr];
    }
    __syncthreads();

    // ---- class boundaries + counts ----
    uint32_t gp = g[t];
    if (gp != 0xFFFFFFFFu) {
        uint32_t labp = gp >> 10;
        atomicAdd(&cnt[labp], 1u);
        if (t == 0 || (g[t - 1] >> 10) != labp) stt[labp] = (uint32_t)t;
    }
    __syncthreads();

    // ---- parallel suppression bitmask: sup[p] bit (q-p-1) = iou(p,q)>thr, same class ----
    {
        ull sp = 0;
        if (gp != 0xFFFFFFFFu) {
            uint32_t labi = gp >> 10;
            uint32_t ri = gp & 1023u;
            float4 oi = ob[ri]; float ai = ar[ri];
            for (int qq = t + 1; qq < 1024; qq++) {
                uint32_t gq = g[qq];
                if ((gq >> 10) != labi) break;
                int dq = qq - t;
                if (dq > 64) { ovr[labi] = 1; break; }
                uint32_t rj = gq & 1023u;
                float4 oj = ob[rj];
                float lx = fmaxf(oi.x, oj.x), ly = fmaxf(oi.y, oj.y);
                float rx = fminf(oi.z, oj.z), ry = fminf(oi.w, oj.w);
                float wx = fmaxf(__fsub_rn(rx, lx), 0.f);
                float wy = fmaxf(__fsub_rn(ry, ly), 0.f);
                float inter = __fmul_rn(wx, wy);
                float uni = __fsub_rn(__fadd_rn(ai, ar[rj]), inter);
                float iou = __fdiv_rn(inter, fmaxf(uni, 1e-9f));
                if (iou > 0.6f) sp |= 1ull << (dq - 1);
            }
        }
        sup[t] = sp;
    }
    __syncthreads();

    // ---- 80-lane register greedy (rank order within class = score order) ----
    if (t < N_CLS) {
        uint32_t n = cnt[t];
        if (n > 0) {
            uint32_t s0 = stt[t];
            if (n <= 64 && !ovr[t]) {
                ull kill = 0;
                for (uint32_t i = 0; i < n; i++) {
                    if (!((kill >> i) & 1ull)) {
                        if (i + 1 < 64) kill |= sup[s0 + i] << (i + 1);
                        keepA[g[s0 + i] & 1023u] = 1;
                    }
                }
            } else {                                  // oversized class: serial fallback
                for (uint32_t i = 0; i < n; i++) {
                    uint32_t ri = g[s0 + i] & 1023u;
                    float4 oi = ob[ri]; float ai = ar[ri];
                    bool kp = true;
                    for (uint32_t m2 = 0; m2 < i && kp; m2++) {
                        uint32_t rm = g[s0 + m2] & 1023u;
                        if (!keepA[rm]) continue;
                        float4 om = ob[rm];
                        float lx = fmaxf(om.x, oi.x), ly = fmaxf(om.y, oi.y);
                        float rx = fminf(om.z, oi.z), ry = fminf(om.w, oi.w);
                        float wx = fmaxf(__fsub_rn(rx, lx), 0.f);
                        float wy = fmaxf(__fsub_rn(ry, ly), 0.f);
                        float inter = __fmul_rn(wx, wy);
                        float uni = __fsub_rn(__fadd_rn(ar[rm], ai), inter);
                        float iou = __fdiv_rn(inter, fmaxf(uni, 1e-9f));
                        if (iou > 0.6f) kp = false;
                    }
                    keepA[ri] = kp ? 1 : 0;
                }
            }
        }
    }
    __syncthreads();

    // ---- masked fp32 output ----
    const bool keep = keepA[t] != 0;
    float v0 = keep ? bx.x : 0.f, v1 = keep ? bx.y : 0.f;
    float v2 = keep ? bx.z : 0.f, v3 = keep ? bx.w : 0.f;
    float v4 = keep ? cf : 0.f, v5 = keep ? lb : 0.f;
    float2* o2 = (float2*)out;
    o2[t * 3 + 0] = make_float2(v0, v1);
    o2[t * 3 + 1] = make_float2(v2, v3);
    o2[t * 3 + 2] = make_float2(v4, v5);
}

extern "C" void kernel_launch(void* const* d_in, const int* in_sizes, int n_in,
                              void* d_out, int out_size, void* d_ws, size_t ws_size,
                              hipStream_t stream) {
    const float* bboxes = (const float*)d_in[0];
    const float* scores = (const float*)d_in[1];
    if (n_in >= 2 && in_sizes[0] > in_sizes[1]) {   // defensive: scores is the 20x larger input
        bboxes = (const float*)d_in[1];
        scores = (const float*)d_in[0];
    }

    if (ws_size < (size_t)WS_REQUIRED) {
        k_sentinel<<<(K_TOP * 6 + 255) / 256, 256, 0, stream>>>(
            (float*)d_out, (float)(ws_size >> 10));
        return;
    }

    char* ws = (char*)d_ws;
    uint32_t* hist   = (uint32_t*)(ws + OFF_HIST);
    uint32_t* ctrl   = (uint32_t*)(ws + OFF_CTRL);
    uint16_t* bins16 = (uint16_t*)(ws + OFF_BINS);
    ull*      list   = (ull*)(ws + OFF_LIST);

    hipMemsetAsync(ws, 0, MEMSET_BYTES, stream);    // hist + ctrl
    k_conf  <<<N_ANCH / 128, 256, 0, stream>>>(scores, bins16, hist);
    k_cut   <<<1,           1024, 0, stream>>>(hist, ctrl);
    k_gather<<<256,          256, 0, stream>>>(scores, bins16, ctrl, list);
    k_final <<<1,           1024, 0, stream>>>((const float4*)bboxes, ctrl, list,
                                               (float*)d_out);
}

// Round 3
// 187.103 us; speedup vs baseline: 1.4583x; 1.0633x over previous
//
#include <hip/hip_runtime.h>
#include <stdint.h>

// YoloNAS postprocess, fp32 in/out — R11.
// memset | k_conf (2048 blk): conf/argmax -> bins16 + SWIZZLED 32k hist
//        | k_cut  (1 blk): cutoff bin + nsel computed ONCE (regs-held bins, shfl scan)
//        | k_gather (256 blk): candidate emit only (reads ctrl[2]=cT)
//        | k_final (1 blk): register bitonic (2/thread for nsort<=2048: 16 waves,
//          conflict-free ulonglong2 LDS passes; 4/thread skewed for 4096) ->
//          popcount-rank class grouping (replaces 55-pass u32 bitonic) ->
//          suppression bitmasks -> 80-lane register greedy -> output
// R11 changes vs R10 (candidate predicate, sort keys, fp32 NMS math identical; absmax 0):
//  (1) class-group bitonic DELETED: g[] is a stable-partition-by-class of a
//      rank-sorted sequence -> per-class 1024-bit masks (cmask[80][16] u64),
//      cnt=popc, stt=80-prefix, within-class rank=popc of lower bits.
//      ~55 barrier passes + boundary atomics -> 5 barriers. Bit-identical g.
//  (2) main sort 2 elems/thread for nsort<=2048 (typ. ncand~1300): 16 waves
//      active (was 8), LDS passes are consecutive ulonglong2 (conflict-free,
//      no skew). nsort=4096 cold path keeps R10 4/thread skewed code.
// Theory: k_final is serial-latency bound (R9: 36% VALU on its CU, 64% stalled);
// cost scales with barrier-separated pass count, not op count.

#define N_ANCH   262144
#define N_CLS    80
#define K_TOP    1024
#define CAP      4096

typedef unsigned long long ull;

// hist layout bijection: bit-rotate 15-bit bin, b = [b14..b11 | b10..b0]
// -> slot = [b10..b0 | b14..b11]. Value-adjacent bins land 16 u32 (64B) apart.
#define HSLOT(b) ((((b) & 2047u) << 4) | ((b) >> 11))
// skewed LDS index for the u64 sort scratch (4096 path only)
#define SKEW(e) ((uint32_t)(e) + ((uint32_t)(e) >> 4))

// ---- workspace layout (bytes); total 688192 < proven ws_size >= 733248 ----
#define OFF_HIST  0           // u32[32768] (swizzled layout)
#define OFF_CTRL  131072      // u32[16]: [0]=cand counter, [1]=nsel, [2]=cutoff bin
#define MEMSET_BYTES 131136
#define OFF_BINS  131136      // u16[262144]: valid?0x8000|bin:0
#define OFF_LIST  655424      // u64[4096] candidate keys
#define WS_REQUIRED 688192

__global__ __launch_bounds__(256) void k_sentinel(float* __restrict__ out, float v) {
    int i = blockIdx.x * 256 + threadIdx.x;
    if (i < K_TOP * 6) out[i] = v;
}

static __device__ __forceinline__ uint32_t conf_key24(float best) {
    uint32_t u = __float_as_uint(best);
    if (u > 0x3F800000u) u = 0x3F800000u;    // defensive; conf in [0.5, 1]
    if (u < 0x3F000000u) u = 0x3F000000u;
    return u - 0x3F000000u;                  // 0..0x800000, monotone in conf
}

static __device__ __forceinline__ void cmpsw(ull& x, ull& y, bool up) {
    ull mn = x < y ? x : y, mx = x < y ? y : x;
    x = up ? mn : mx; y = up ? mx : mn;
}

// ---------- kernel 1: conf/argmax, 16 lanes/anchor, 128 anchors/block ----------
__global__ __launch_bounds__(256) void k_conf(const float* __restrict__ scores,
                                              uint16_t* __restrict__ bins16,
                                              uint32_t* __restrict__ hist) {
    const int t = threadIdx.x;
    const int r = t >> 4, s = t & 15;
    const int a0 = blockIdx.x * 128 + r;
    const float* base = scores + (size_t)a0 * N_CLS;
    float4 v0 = ((const float4*)base)[s];
    float4 v1;
    if (s < 4) v1 = ((const float4*)base)[16 + s];
    #pragma unroll
    for (int i = 0; i < 8; i++) {
        float4 c0 = v0, c1 = v1;
        if (i + 1 < 8) {                              // software-pipeline next tile
            const float* nb = base + (size_t)(i + 1) * 16 * N_CLS;
            v0 = ((const float4*)nb)[s];
            if (s < 4) v1 = ((const float4*)nb)[16 + s];
        }
        float best = c0.x; int lab = 4 * s;           // first-max (strict >)
        if (c0.y > best) { best = c0.y; lab = 4 * s + 1; }
        if (c0.z > best) { best = c0.z; lab = 4 * s + 2; }
        if (c0.w > best) { best = c0.w; lab = 4 * s + 3; }
        if (s < 4) {
            const int c = 64 + 4 * s;
            if (c1.x > best) { best = c1.x; lab = c; }
            if (c1.y > best) { best = c1.y; lab = c + 1; }
            if (c1.z > best) { best = c1.z; lab = c + 2; }
            if (c1.w > best) { best = c1.w; lab = c + 3; }
        }
        ull key = ((ull)(uint32_t)__float_as_uint(best) << 7) | (ull)(uint32_t)(127 - lab);
        ull o;
        o = __shfl_xor(key, 1); if (o > key) key = o;
        o = __shfl_xor(key, 2); if (o > key) key = o;
        o = __shfl_xor(key, 4); if (o > key) key = o;
        o = __shfl_xor(key, 8); if (o > key) key = o;
        if (s == 0) {
            const int a = a0 + i * 16;
            float bv = __uint_as_float((uint32_t)(key >> 7));
            uint16_t pk = 0;
            if (bv >= 0.5f) {
                uint32_t bin = conf_key24(bv) >> 8;
                if (bin > 32767u) bin = 32767u;
                atomicAdd(&hist[HSLOT(bin)], 1u);     // swizzled slot, linear bin number
                pk = (uint16_t)(0x8000u | bin);
            }
            bins16[a] = pk;
        }
    }
}

// ---------- kernel 2: cutoff bin + nsel, once (1 block, 1024 threads) ----------
__global__ __launch_bounds__(1024) void k_cut(const uint32_t* __restrict__ hist,
                                              uint32_t* __restrict__ ctrl) {
    __shared__ uint32_t wtot[16], wsuf[16];
    const int t = threadIdx.x;
    const int lane = t & 63, w = t >> 6;
    // bins b = 32t + i: b>>11 = t>>6 (const), b&2047 = 32(t&63)+i
    // slot = ((t&63)<<9) | (i<<4) | (t>>6)
    const uint32_t sbase = (((uint32_t)t & 63u) << 9) | ((uint32_t)t >> 6);
    uint32_t c[32];
    #pragma unroll
    for (int i = 0; i < 32; i++) c[i] = hist[sbase | ((uint32_t)i << 4)];
    uint32_t part = 0;
    #pragma unroll
    for (int i = 0; i < 32; i++) part += c[i];
    // wave inclusive suffix scan: x = sum of part over lanes >= lane (this wave)
    uint32_t x = part;
    #pragma unroll
    for (int d = 1; d < 64; d <<= 1) {
        uint32_t o = __shfl_down(x, d);
        if (lane + d < 64) x += o;
    }
    if (lane == 0) wtot[w] = x;                       // wave total
    __syncthreads();
    if (t < 16) {
        uint32_t s = 0;
        for (int ww = t + 1; ww < 16; ww++) s += wtot[ww];
        wsuf[t] = s;                                  // waves strictly above
        if (t == 0) {
            uint32_t total = s + wtot[0];
            ctrl[1] = (total < K_TOP) ? total : K_TOP;   // nsel
        }
    }
    __syncthreads();
    uint32_t run = (x + wsuf[w]) - part;              // count strictly above my segment
    if (run < K_TOP && run + part >= K_TOP) {         // unique crossing thread
        uint32_t fnd = 0, cbv = 0;
        #pragma unroll
        for (int i = 31; i >= 0; i--) {               // descending bins, register scan
            if (!fnd && run + c[i] >= K_TOP) { cbv = (uint32_t)(t * 32 + i); fnd = 1; }
            if (!fnd) run += c[i];
        }
        ctrl[2] = cbv;                                // cutoff bin (cT)
    }
    // total < K_TOP: no writer; ctrl[2] stays 0 from memset -> include everything
}

// ---------- kernel 3: candidate emit only ----------
__global__ __launch_bounds__(256) void k_gather(const float* __restrict__ scores,
                                                const uint16_t* __restrict__ bins16,
                                                uint32_t* __restrict__ ctrl,
                                                ull* __restrict__ list) {
    __shared__ uint32_t lcnt, lbase;
    const int t = threadIdx.x, b = blockIdx.x;
    if (t == 0) { lcnt = 0; lbase = 0; }
    __syncthreads();
    const uint32_t cT = ctrl[2];
    // scan my 4-anchor slice, re-derive exact keys for hits; collect in registers
    const int a4 = b * 256 + t;
    ushort4 pk4 = ((const ushort4*)bins16)[a4];
    uint16_t pk[4] = {pk4.x, pk4.y, pk4.z, pk4.w};
    ull      hk[4];                                   // keys  (compile-time indexed)
    uint32_t hs[4];                                   // local slots
    bool     hv[4];                                   // valid
    #pragma unroll
    for (int e = 0; e < 4; e++) {
        hv[e] = false; hk[e] = 0; hs[e] = 0;
        uint32_t u = pk[e];
        if ((u & 0x8000u) && (u & 0x7FFFu) >= cT) {
            const uint32_t a = (uint32_t)a4 * 4u + (uint32_t)e;
            const float4* row = (const float4*)(scores + (size_t)a * N_CLS);
            float best = -1.f; int lab = 0;
            for (int f = 0; f < 20; f++) {
                float4 w = row[f];
                if (w.x > best) { best = w.x; lab = 4 * f; }
                if (w.y > best) { best = w.y; lab = 4 * f + 1; }
                if (w.z > best) { best = w.z; lab = 4 * f + 2; }
                if (w.w > best) { best = w.w; lab = 4 * f + 3; }
            }
            if (best >= 0.5f) {
                uint32_t k24 = conf_key24(best);
                hk[e] = ((ull)(0x1000000u - k24) << 25) | ((ull)a << 7)
                      | (ull)(uint32_t)lab;           // ascending = conf desc, idx asc
                hs[e] = atomicAdd(&lcnt, 1u);         // LDS: ~5 hits/block
                hv[e] = true;
            }
        }
    }
    __syncthreads();
    if (t == 0 && lcnt) lbase = atomicAdd(&ctrl[0], lcnt);  // ONE global atomic/block
    __syncthreads();
    const uint32_t base2 = lbase;
    #pragma unroll
    for (int e = 0; e < 4; e++) {
        if (hv[e]) {
            uint32_t slot = base2 + hs[e];
            if (slot < CAP) list[slot] = hk[e];       // list order irrelevant: k_final sorts
        }
    }
}

// ---------- kernel 4: sort + group + class-bitmask NMS + output (1 block) ----------
// LDS: sort scratch sk u64[4352 skewed max]@0 (34816B, dead after extract); then
// ob f4[1024]@0 | ar f[1024]@16384 | red16 f[16]@20480 | g u32[1024]@20544 |
// sup u64[1024]@24640 | keepA u8[1024]@32832 | cnt u32[80]@33856 | stt u32[80]@34176 |
// ovr u8[80]@34496 | cmask u64[80][16]@34816 (10240B)
__global__ __launch_bounds__(1024) void k_final(const float4* __restrict__ bboxes,
                                                const uint32_t* __restrict__ ctrl,
                                                const ull* __restrict__ list,
                                                float* __restrict__ out) {
    __shared__ __align__(16) char smem[45056];
    ull*      sk    = (ull*)smem;
    float4*   ob    = (float4*)smem;
    float*    ar    = (float*)(smem + 16384);
    float*    red16 = (float*)(smem + 20480);
    uint32_t* g     = (uint32_t*)(smem + 20544);
    ull*      sup   = (ull*)(smem + 24640);
    uint8_t*  keepA = (uint8_t*)(smem + 32832);
    uint32_t* cnt   = (uint32_t*)(smem + 33856);
    uint32_t* stt   = (uint32_t*)(smem + 34176);
    uint8_t*  ovr   = (uint8_t*)(smem + 34496);
    ull*      cmask = (ull*)(smem + 34816);           // [80][16] bit t = rank t present
    const int t = threadIdx.x;
    const uint32_t nsel = ctrl[1];
    uint32_t ncand = ctrl[0]; if (ncand > CAP) ncand = CAP;

    // ---- adaptive register bitonic: nsort = pow2 >= ncand (>=1024) ----
    uint32_t nsort = 1024;
    while (nsort < ncand) nsort <<= 1;                // 1024 / 2048 / 4096 (uniform)

    if (nsort <= 2048) {
        // ---- 2 elems/thread: TS2 threads (all 16 waves at nsort=2048) ----
        const int TS2 = (int)(nsort >> 1);
        ull E0 = ~0ull, E1 = ~0ull;
        if (t < TS2) {
            int e = 2 * t;
            E0 = (e < (int)ncand)     ? list[e]     : ~0ull;
            E1 = (e + 1 < (int)ncand) ? list[e + 1] : ~0ull;
        }
        for (uint32_t k = 2; k <= nsort; k <<= 1) {
            for (uint32_t j = k >> 1; j > 0; j >>= 1) {
                if (j >= 128) {                       // cross-wave: LDS (ulonglong2, linear)
                    __syncthreads();
                    if (t < TS2) {
                        ulonglong2 wv; wv.x = E0; wv.y = E1;
                        *(ulonglong2*)&sk[2 * t] = wv;
                    }
                    __syncthreads();
                    if (t < TS2) {
                        uint32_t e0 = 2 * t;
                        ulonglong2 rv = *(const ulonglong2*)&sk[e0 ^ j];  // j even
                        bool km = (((e0 & k) == 0) != ((e0 & j) == 0));   // same for e0,e0+1
                        E0 = ((E0 > rv.x) == km) ? E0 : rv.x;
                        E1 = ((E1 > rv.y) == km) ? E1 : rv.y;
                    }
                } else if (t < TS2) {
                    if (j >= 2) {                     // in-wave: shfl_xor d=j/2 (<=32)
                        int d = (int)(j >> 1);
                        bool km = ((((2 * t) & k) == 0) != (((2 * t) & j) == 0));
                        ull o0 = __shfl_xor(E0, d);
                        ull o1 = __shfl_xor(E1, d);
                        E0 = ((E0 > o0) == km) ? E0 : o0;
                        E1 = ((E1 > o1) == km) ? E1 : o1;
                    } else {                          // j==1: in-thread
                        bool up = (((2 * t) & k) == 0);
                        cmpsw(E0, E1, up);
                    }
                }
            }
        }
        __syncthreads();
        if (t < TS2) {
            ulonglong2 wv; wv.x = E0; wv.y = E1;
            *(ulonglong2*)&sk[2 * t] = wv;
        }
    } else {
        // ---- cold path nsort==4096: 4 elems/thread, skewed LDS (R10 code) ----
        const int TS = (int)(nsort >> 2);
        ull E[4];
        if (t < TS) {
            #pragma unroll
            for (int rr = 0; rr < 4; rr++) {
                int e = 4 * t + rr;
                E[rr] = (e < (int)ncand) ? list[e] : ~0ull;
            }
        }
        for (uint32_t k = 2; k <= nsort; k <<= 1) {
            for (uint32_t j = k >> 1; j > 0; j >>= 1) {
                if (j >= 256) {
                    __syncthreads();
                    if (t < TS) {
                        #pragma unroll
                        for (int rr = 0; rr < 4; rr++) sk[SKEW(4 * t + rr)] = E[rr];
                    }
                    __syncthreads();
                    if (t < TS) {
                        #pragma unroll
                        for (int rr = 0; rr < 4; rr++) {
                            uint32_t e = 4 * t + rr;
                            ull o = sk[SKEW(e ^ j)];
                            bool keepMax = (((e & k) == 0) != ((e & j) == 0));
                            bool gt = E[rr] > o;
                            E[rr] = (gt == keepMax) ? E[rr] : o;
                        }
                    }
                } else if (t < TS) {
                    if (j >= 4) {
                        int d = (int)(j >> 2);
                        #pragma unroll
                        for (int rr = 0; rr < 4; rr++) {
                            uint32_t e = 4 * t + rr;
                            ull o = __shfl_xor(E[rr], d);
                            bool keepMax = (((e & k) == 0) != ((e & j) == 0));
                            bool gt = E[rr] > o;
                            E[rr] = (gt == keepMax) ? E[rr] : o;
                        }
                    } else if (j == 2) {
                        bool up = (((4 * t) & k) == 0);
                        cmpsw(E[0], E[2], up); cmpsw(E[1], E[3], up);
                    } else {
                        bool upA = (((4 * t) & k) == 0);
                        bool upB = (((4 * t + 2) & k) == 0);
                        cmpsw(E[0], E[1], upA);
                        cmpsw(E[2], E[3], upB);
                    }
                }
            }
        }
        __syncthreads();
        if (t < TS) {
            #pragma unroll
            for (int rr = 0; rr < 4; rr++) sk[SKEW(4 * t + rr)] = E[rr];
        }
    }
    __syncthreads();
    ull skey = (nsort <= 2048) ? sk[t] : sk[SKEW(t)]; // rank t (t < 1024 <= nsort)
    __syncthreads();                                  // sk region free for reuse

    // ---- extract + gather + prep (exact reference fp32 order; max is associative) ----
    float4 bx = make_float4(0.f, 0.f, 0.f, 0.f);
    float cf = 0.f, lb = 0.f;
    uint32_t lab = 0;
    if ((uint32_t)t < nsel) {
        uint32_t idx = (uint32_t)(skey >> 7) & 0x3FFFFu;
        lab = (uint32_t)skey & 127u;
        cf = __uint_as_float(0x3F000000u + (0x1000000u - (uint32_t)(skey >> 25)));
        lb = (float)lab;
        bx = bboxes[idx];
    }
    float m = fmaxf(fmaxf(bx.x, bx.y), fmaxf(bx.z, bx.w));
    for (int d = 32; d > 0; d >>= 1) m = fmaxf(m, __shfl_xor(m, d));
    if ((t & 63) == 0) red16[t >> 6] = m;
    __syncthreads();
    float M = red16[0];
    #pragma unroll
    for (int w = 1; w < 16; w++) M = fmaxf(M, red16[w]);
    M = __fadd_rn(M, 1.0f);
    float o = __fmul_rn(lb, M);
    float4 q;
    q.x = __fadd_rn(bx.x, o); q.y = __fadd_rn(bx.y, o);
    q.z = __fadd_rn(bx.z, o); q.w = __fadd_rn(bx.w, o);
    ob[t] = q;
    ar[t] = __fmul_rn(__fsub_rn(q.z, q.x), __fsub_rn(q.w, q.y));
    g[t] = 0xFFFFFFFFu;                               // scatter target, init invalid
    if (t < N_CLS) ovr[t] = 0;
    keepA[t] = 0;
    if (t < 640) {                                    // zero cmask[80][16] (1280 u64)
        ulonglong2 z; z.x = 0; z.y = 0;
        *(ulonglong2*)&cmask[2 * t] = z;
    }
    __syncthreads();

    // ---- popcount-rank class grouping (replaces 55-pass u32 bitonic) ----
    // g := stable partition by class of the rank-sorted sequence; bit-identical
    // to sorting (lab<<10|t) ascending.
    if ((uint32_t)t < nsel)
        atomicOr(&cmask[lab * 16 + (t >> 6)], 1ull << (t & 63));
    __syncthreads();
    if (t < N_CLS) {                                  // per-class counts
        uint32_t s = 0;
        #pragma unroll
        for (int w = 0; w < 16; w++) s += (uint32_t)__popcll(cmask[t * 16 + w]);
        cnt[t] = s;
    }
    __syncthreads();
    if (t < N_CLS) {                                  // exclusive prefix (starts)
        uint32_t s = 0;
        for (int i = 0; i < N_CLS - 1; i++) {
            uint32_t v = cnt[i];                      // broadcast read
            if (i < t) s += v;
        }
        stt[t] = s;
    }
    __syncthreads();
    if ((uint32_t)t < nsel) {                         // within-class rank + scatter
        const ull* cm = &cmask[lab * 16];
        uint32_t w = (uint32_t)t >> 6;
        uint32_t r = (uint32_t)__popcll(cm[w] & ((1ull << (t & 63)) - 1ull));
        for (uint32_t ww = 0; ww < w; ww++) r += (uint32_t)__popcll(cm[ww]);
        g[stt[lab] + r] = (lab << 10) | (uint32_t)t;
    }
    __syncthreads();

    // ---- parallel suppression bitmask: sup[p] bit (q-p-1) = iou(p,q)>thr, same class ----
    uint32_t gp = g[t];
    {
        ull sp = 0;
        if (gp != 0xFFFFFFFFu) {
            uint32_t labi = gp >> 10;
            uint32_t ri = gp & 1023u;
            float4 oi = ob[ri]; float ai = ar[ri];
            for (int qq = t + 1; qq < 1024; qq++) {
                uint32_t gq = g[qq];
                if ((gq >> 10) != labi) break;
                int dq = qq - t;
                if (dq > 64) { ovr[labi] = 1; break; }
                uint32_t rj = gq & 1023u;
                float4 oj = ob[rj];
                float lx = fmaxf(oi.x, oj.x), ly = fmaxf(oi.y, oj.y);
                float rx = fminf(oi.z, oj.z), ry = fminf(oi.w, oj.w);
                float wx = fmaxf(__fsub_rn(rx, lx), 0.f);
                float wy = fmaxf(__fsub_rn(ry, ly), 0.f);
                float inter = __fmul_rn(wx, wy);
                float uni = __fsub_rn(__fadd_rn(ai, ar[rj]), inter);
                float iou = __fdiv_rn(inter, fmaxf(uni, 1e-9f));
                if (iou > 0.6f) sp |= 1ull << (dq - 1);
            }
        }
        sup[t] = sp;
    }
    __syncthreads();

    // ---- 80-lane register greedy (rank order within class = score order) ----
    if (t < N_CLS) {
        uint32_t n = cnt[t];
        if (n > 0) {
            uint32_t s0 = stt[t];
            if (n <= 64 && !ovr[t]) {
                ull kill = 0;
                for (uint32_t i = 0; i < n; i++) {
                    if (!((kill >> i) & 1ull)) {
                        if (i + 1 < 64) kill |= sup[s0 + i] << (i + 1);
                        keepA[g[s0 + i] & 1023u] = 1;
                    }
                }
            } else {                                  // oversized class: serial fallback
                for (uint32_t i = 0; i < n; i++) {
                    uint32_t ri = g[s0 + i] & 1023u;
                    float4 oi = ob[ri]; float ai = ar[ri];
                    bool kp = true;
                    for (uint32_t m2 = 0; m2 < i && kp; m2++) {
                        uint32_t rm = g[s0 + m2] & 1023u;
                        if (!keepA[rm]) continue;
                        float4 om = ob[rm];
                        float lx = fmaxf(om.x, oi.x), ly = fmaxf(om.y, oi.y);
                        float rx = fminf(om.z, oi.z), ry = fminf(om.w, oi.w);
                        float wx = fmaxf(__fsub_rn(rx, lx), 0.f);
                        float wy = fmaxf(__fsub_rn(ry, ly), 0.f);
                        float inter = __fmul_rn(wx, wy);
                        float uni = __fsub_rn(__fadd_rn(ar[rm], ai), inter);
                        float iou = __fdiv_rn(inter, fmaxf(uni, 1e-9f));
                        if (iou > 0.6f) kp = false;
                    }
                    keepA[ri] = kp ? 1 : 0;
                }
            }
        }
    }
    __syncthreads();

    // ---- masked fp32 output ----
    const bool keep = keepA[t] != 0;
    float v0 = keep ? bx.x : 0.f, v1 = keep ? bx.y : 0.f;
    float v2 = keep ? bx.z : 0.f, v3 = keep ? bx.w : 0.f;
    float v4 = keep ? cf : 0.f, v5 = keep ? lb : 0.f;
    float2* o2 = (float2*)out;
    o2[t * 3 + 0] = make_float2(v0, v1);
    o2[t * 3 + 1] = make_float2(v2, v3);
    o2[t * 3 + 2] = make_float2(v4, v5);
}

extern "C" void kernel_launch(void* const* d_in, const int* in_sizes, int n_in,
                              void* d_out, int out_size, void* d_ws, size_t ws_size,
                              hipStream_t stream) {
    const float* bboxes = (const float*)d_in[0];
    const float* scores = (const float*)d_in[1];
    if (n_in >= 2 && in_sizes[0] > in_sizes[1]) {   // defensive: scores is the 20x larger input
        bboxes = (const float*)d_in[1];
        scores = (const float*)d_in[0];
    }

    if (ws_size < (size_t)WS_REQUIRED) {
        k_sentinel<<<(K_TOP * 6 + 255) / 256, 256, 0, stream>>>(
            (float*)d_out, (float)(ws_size >> 10));
        return;
    }

    char* ws = (char*)d_ws;
    uint32_t* hist   = (uint32_t*)(ws + OFF_HIST);
    uint32_t* ctrl   = (uint32_t*)(ws + OFF_CTRL);
    uint16_t* bins16 = (uint16_t*)(ws + OFF_BINS);
    ull*      list   = (ull*)(ws + OFF_LIST);

    hipMemsetAsync(ws, 0, MEMSET_BYTES, stream);    // hist + ctrl
    k_conf  <<<N_ANCH / 128, 256, 0, stream>>>(scores, bins16, hist);
    k_cut   <<<1,           1024, 0, stream>>>(hist, ctrl);
    k_gather<<<256,          256, 0, stream>>>(scores, bins16, ctrl, list);
    k_final <<<1,           1024, 0, stream>>>((const float4*)bboxes, ctrl, list,
                                               (float*)d_out);
}

// Round 4
// 181.459 us; speedup vs baseline: 1.5037x; 1.0311x over previous
//
#include <hip/hip_runtime.h>
#include <stdint.h>

// YoloNAS postprocess, fp32 in/out — R12.
// memset | k_conf (2048 blk): conf/argmax -> bins16 + SWIZZLED 32k hist
//          DEPTH-4 load pipeline (MLP fix: 2 -> 8 loads in flight per wave)
//        | k_cut  (1 blk): cutoff bin + nsel computed ONCE (regs-held bins, shfl scan)
//        | k_gather (256 blk): candidate emit only (reads ctrl[2]=cT)
//        | k_final (1 blk): COUNTING-RANK sort (candidates span <2048 ulp of conf:
//          hist 2048 slots + prefix + scatter + per-slot tie insertion; ~7 barriers
//          vs 66-pass bitonic; bitonic kept as guarded fallback) ->
//          popcount-rank class grouping -> suppression bitmasks -> greedy -> output
// R12 changes vs R11 (candidate predicate, sort keys, fp32 NMS math identical; absmax 0):
//  (1) k_conf depth-4 prefetch ring v0[4]/v1[4]: theory = latency-bound (Little's law:
//      ~1-2KB/CU in flight vs ~15KB needed for 6.3TB/s). +32 VGPR, stays <=64.
//  (2) k_final counting-rank: cutoff bin is ~4 bins below top (count/bin~320) so
//      k24c = 0x800000-k24 < ~1100 for all cands -> exact-ulp counting sort with
//      tie fix-up. Order bit-identical to bitonic (conf desc, anchor asc).
//      Fallback: range>=2048 or slot depth>=16 -> R11 bitonic path unchanged.

#define N_ANCH   262144
#define N_CLS    80
#define K_TOP    1024
#define CAP      4096

typedef unsigned long long ull;

// hist layout bijection: bit-rotate 15-bit bin, b = [b14..b11 | b10..b0]
// -> slot = [b10..b0 | b14..b11]. Value-adjacent bins land 16 u32 (64B) apart.
#define HSLOT(b) ((((b) & 2047u) << 4) | ((b) >> 11))
// skewed LDS index for the u64 sort scratch (bitonic 4096 path only)
#define SKEW(e) ((uint32_t)(e) + ((uint32_t)(e) >> 4))

// ---- workspace layout (bytes); total 688192 < proven ws_size >= 733248 ----
#define OFF_HIST  0           // u32[32768] (swizzled layout)
#define OFF_CTRL  131072      // u32[16]: [0]=cand counter, [1]=nsel, [2]=cutoff bin
#define MEMSET_BYTES 131136
#define OFF_BINS  131136      // u16[262144]: valid?0x8000|bin:0
#define OFF_LIST  655424      // u64[4096] candidate keys
#define WS_REQUIRED 688192

__global__ __launch_bounds__(256) void k_sentinel(float* __restrict__ out, float v) {
    int i = blockIdx.x * 256 + threadIdx.x;
    if (i < K_TOP * 6) out[i] = v;
}

static __device__ __forceinline__ uint32_t conf_key24(float best) {
    uint32_t u = __float_as_uint(best);
    if (u > 0x3F800000u) u = 0x3F800000u;    // defensive; conf in [0.5, 1]
    if (u < 0x3F000000u) u = 0x3F000000u;
    return u - 0x3F000000u;                  // 0..0x800000, monotone in conf
}

static __device__ __forceinline__ void cmpsw(ull& x, ull& y, bool up) {
    ull mn = x < y ? x : y, mx = x < y ? y : x;
    x = up ? mn : mx; y = up ? mx : mn;
}

// ---------- kernel 1: conf/argmax, 16 lanes/anchor, 128 anchors/block ----------
__global__ __launch_bounds__(256) void k_conf(const float* __restrict__ scores,
                                              uint16_t* __restrict__ bins16,
                                              uint32_t* __restrict__ hist) {
    const int t = threadIdx.x;
    const int r = t >> 4, s = t & 15;
    const int a0 = blockIdx.x * 128 + r;
    const float* base = scores + (size_t)a0 * N_CLS;
    // depth-4 software pipeline: 8 (v0) + 2 (v1, s<4) loads in flight per lane group
    float4 v0[4], v1[4];
    #pragma unroll
    for (int p = 0; p < 4; p++) {
        const float* nb = base + (size_t)p * 16 * N_CLS;
        v0[p] = ((const float4*)nb)[s];
        if (s < 4) v1[p] = ((const float4*)nb)[16 + s];
    }
    #pragma unroll
    for (int i = 0; i < 8; i++) {
        float4 c0 = v0[i & 3], c1 = v1[i & 3];
        if (i + 4 < 8) {                              // refill ring 4 tiles ahead
            const float* nb = base + (size_t)(i + 4) * 16 * N_CLS;
            v0[i & 3] = ((const float4*)nb)[s];
            if (s < 4) v1[i & 3] = ((const float4*)nb)[16 + s];
        }
        float best = c0.x; int lab = 4 * s;           // first-max (strict >)
        if (c0.y > best) { best = c0.y; lab = 4 * s + 1; }
        if (c0.z > best) { best = c0.z; lab = 4 * s + 2; }
        if (c0.w > best) { best = c0.w; lab = 4 * s + 3; }
        if (s < 4) {
            const int c = 64 + 4 * s;
            if (c1.x > best) { best = c1.x; lab = c; }
            if (c1.y > best) { best = c1.y; lab = c + 1; }
            if (c1.z > best) { best = c1.z; lab = c + 2; }
            if (c1.w > best) { best = c1.w; lab = c + 3; }
        }
        ull key = ((ull)(uint32_t)__float_as_uint(best) << 7) | (ull)(uint32_t)(127 - lab);
        ull o;
        o = __shfl_xor(key, 1); if (o > key) key = o;
        o = __shfl_xor(key, 2); if (o > key) key = o;
        o = __shfl_xor(key, 4); if (o > key) key = o;
        o = __shfl_xor(key, 8); if (o > key) key = o;
        if (s == 0) {
            const int a = a0 + i * 16;
            float bv = __uint_as_float((uint32_t)(key >> 7));
            uint16_t pk = 0;
            if (bv >= 0.5f) {
                uint32_t bin = conf_key24(bv) >> 8;
                if (bin > 32767u) bin = 32767u;
                atomicAdd(&hist[HSLOT(bin)], 1u);     // swizzled slot, linear bin number
                pk = (uint16_t)(0x8000u | bin);
            }
            bins16[a] = pk;
        }
    }
}

// ---------- kernel 2: cutoff bin + nsel, once (1 block, 1024 threads) ----------
__global__ __launch_bounds__(1024) void k_cut(const uint32_t* __restrict__ hist,
                                              uint32_t* __restrict__ ctrl) {
    __shared__ uint32_t wtot[16], wsuf[16];
    const int t = threadIdx.x;
    const int lane = t & 63, w = t >> 6;
    // bins b = 32t + i: b>>11 = t>>6 (const), b&2047 = 32(t&63)+i
    // slot = ((t&63)<<9) | (i<<4) | (t>>6)
    const uint32_t sbase = (((uint32_t)t & 63u) << 9) | ((uint32_t)t >> 6);
    uint32_t c[32];
    #pragma unroll
    for (int i = 0; i < 32; i++) c[i] = hist[sbase | ((uint32_t)i << 4)];
    uint32_t part = 0;
    #pragma unroll
    for (int i = 0; i < 32; i++) part += c[i];
    // wave inclusive suffix scan: x = sum of part over lanes >= lane (this wave)
    uint32_t x = part;
    #pragma unroll
    for (int d = 1; d < 64; d <<= 1) {
        uint32_t o = __shfl_down(x, d);
        if (lane + d < 64) x += o;
    }
    if (lane == 0) wtot[w] = x;                       // wave total
    __syncthreads();
    if (t < 16) {
        uint32_t s = 0;
        for (int ww = t + 1; ww < 16; ww++) s += wtot[ww];
        wsuf[t] = s;                                  // waves strictly above
        if (t == 0) {
            uint32_t total = s + wtot[0];
            ctrl[1] = (total < K_TOP) ? total : K_TOP;   // nsel
        }
    }
    __syncthreads();
    uint32_t run = (x + wsuf[w]) - part;              // count strictly above my segment
    if (run < K_TOP && run + part >= K_TOP) {         // unique crossing thread
        uint32_t fnd = 0, cbv = 0;
        #pragma unroll
        for (int i = 31; i >= 0; i--) {               // descending bins, register scan
            if (!fnd && run + c[i] >= K_TOP) { cbv = (uint32_t)(t * 32 + i); fnd = 1; }
            if (!fnd) run += c[i];
        }
        ctrl[2] = cbv;                                // cutoff bin (cT)
    }
    // total < K_TOP: no writer; ctrl[2] stays 0 from memset -> include everything
}

// ---------- kernel 3: candidate emit only ----------
__global__ __launch_bounds__(256) void k_gather(const float* __restrict__ scores,
                                                const uint16_t* __restrict__ bins16,
                                                uint32_t* __restrict__ ctrl,
                                                ull* __restrict__ list) {
    __shared__ uint32_t lcnt, lbase;
    const int t = threadIdx.x, b = blockIdx.x;
    if (t == 0) { lcnt = 0; lbase = 0; }
    __syncthreads();
    const uint32_t cT = ctrl[2];
    // scan my 4-anchor slice, re-derive exact keys for hits; collect in registers
    const int a4 = b * 256 + t;
    ushort4 pk4 = ((const ushort4*)bins16)[a4];
    uint16_t pk[4] = {pk4.x, pk4.y, pk4.z, pk4.w};
    ull      hk[4];                                   // keys  (compile-time indexed)
    uint32_t hs[4];                                   // local slots
    bool     hv[4];                                   // valid
    #pragma unroll
    for (int e = 0; e < 4; e++) {
        hv[e] = false; hk[e] = 0; hs[e] = 0;
        uint32_t u = pk[e];
        if ((u & 0x8000u) && (u & 0x7FFFu) >= cT) {
            const uint32_t a = (uint32_t)a4 * 4u + (uint32_t)e;
            const float4* row = (const float4*)(scores + (size_t)a * N_CLS);
            float best = -1.f; int lab = 0;
            for (int f = 0; f < 20; f++) {
                float4 w = row[f];
                if (w.x > best) { best = w.x; lab = 4 * f; }
                if (w.y > best) { best = w.y; lab = 4 * f + 1; }
                if (w.z > best) { best = w.z; lab = 4 * f + 2; }
                if (w.w > best) { best = w.w; lab = 4 * f + 3; }
            }
            if (best >= 0.5f) {
                uint32_t k24 = conf_key24(best);
                hk[e] = ((ull)(0x1000000u - k24) << 25) | ((ull)a << 7)
                      | (ull)(uint32_t)lab;           // ascending = conf desc, idx asc
                hs[e] = atomicAdd(&lcnt, 1u);         // LDS: ~5 hits/block
                hv[e] = true;
            }
        }
    }
    __syncthreads();
    if (t == 0 && lcnt) lbase = atomicAdd(&ctrl[0], lcnt);  // ONE global atomic/block
    __syncthreads();
    const uint32_t base2 = lbase;
    #pragma unroll
    for (int e = 0; e < 4; e++) {
        if (hv[e]) {
            uint32_t slot = base2 + hs[e];
            if (slot < CAP) list[slot] = hk[e];       // list order irrelevant: k_final sorts
        }
    }
}

// ---------- kernel 4: sort + group + class-bitmask NMS + output (1 block) ----------
// LDS (sort phase): sk u64[4352]@0 (34816, linear for counting / skewed for bitonic) |
//   hist2 u32[2048]@34816 | gfail u32@43008 | wtot u32[16]@43012 | wbase u32[16]@43076
// LDS (post-sort, reuses everything): ob f4[1024]@0 | ar f[1024]@16384 |
//   red16 f[16]@20480 | g u32[1024]@20544 | sup u64[1024]@24640 | keepA u8[1024]@32832 |
//   cnt u32[80]@33856 | stt u32[80]@34176 | ovr u8[80]@34496 | cmask u64[80][16]@34816
__global__ __launch_bounds__(1024) void k_final(const float4* __restrict__ bboxes,
                                                const uint32_t* __restrict__ ctrl,
                                                const ull* __restrict__ list,
                                                float* __restrict__ out) {
    __shared__ __align__(16) char smem[45056];
    ull*      sk    = (ull*)smem;
    float4*   ob    = (float4*)smem;
    float*    ar    = (float*)(smem + 16384);
    float*    red16 = (float*)(smem + 20480);
    uint32_t* g     = (uint32_t*)(smem + 20544);
    ull*      sup   = (ull*)(smem + 24640);
    uint8_t*  keepA = (uint8_t*)(smem + 32832);
    uint32_t* cnt   = (uint32_t*)(smem + 33856);
    uint32_t* stt   = (uint32_t*)(smem + 34176);
    uint8_t*  ovr   = (uint8_t*)(smem + 34496);
    ull*      cmask = (ull*)(smem + 34816);           // [80][16] bit t = rank t present
    uint32_t* hist2 = (uint32_t*)(smem + 34816);      // sort phase only
    uint32_t* gfail = (uint32_t*)(smem + 43008);
    uint32_t* wtot2 = (uint32_t*)(smem + 43012);
    uint32_t* wbase = (uint32_t*)(smem + 43076);
    const int t = threadIdx.x;
    const uint32_t nsel = ctrl[1];
    uint32_t ncand = ctrl[0]; if (ncand > CAP) ncand = CAP;

    // ================= counting-rank sort (fast path) =================
    // All candidate keys have key>>25 = 0x1000000-k24 with k24c = 0x800000-k24
    // expected < ~1100 (cutoff ~4 bins below top). Rank = #smaller (k24c,anchor).
    ((uint2*)hist2)[t] = make_uint2(0u, 0u);          // zero 2048 slots
    if (t == 0) *gfail = 0;
    __syncthreads();
    ull      keys[4]; uint32_t kcs[4], olds[4]; bool val[4];
    #pragma unroll
    for (int e = 0; e < 4; e++) {
        int i = t + 1024 * e;
        val[e] = (i < (int)ncand); keys[e] = 0; kcs[e] = 0; olds[e] = 0;
        if (val[e]) {
            ull kk = list[i];
            keys[e] = kk;
            uint32_t kc = (uint32_t)(kk >> 25) - 0x800000u;
            if (kc >= 2048u) { *gfail = 1; val[e] = false; }
            else {
                kcs[e] = kc;
                uint32_t od = atomicAdd(&hist2[kc], 1u);
                olds[e] = od;
                if (od >= 16u) *gfail = 1;            // slot too deep: fallback
            }
        }
    }
    __syncthreads();
    const bool ctOK = (*gfail == 0);                  // uniform across block

    if (ctOK) {
        // ---- exclusive prefix over 2048 slots (2/thread, wave scan) ----
        uint32_t v0h = hist2[2 * t], v1h = hist2[2 * t + 1];
        uint32_t sseg = v0h + v1h;
        uint32_t incl = sseg;
        const int lane = t & 63, w = t >> 6;
        #pragma unroll
        for (int d = 1; d < 64; d <<= 1) {
            uint32_t o = __shfl_up(incl, d);
            if (lane >= d) incl += o;
        }
        if (lane == 63) wtot2[w] = incl;
        __syncthreads();
        if (t < 16) {
            uint32_t sb = 0;
            for (int i = 0; i < 16; i++) { uint32_t v = wtot2[i]; if (i < t) sb += v; }
            wbase[t] = sb;
        }
        __syncthreads();
        uint32_t ex = wbase[w] + incl - sseg;         // exclusive before slot 2t
        hist2[2 * t]     = ex;
        hist2[2 * t + 1] = ex + v0h;
        __syncthreads();
        // ---- scatter to rank (arrival order within slot) ----
        #pragma unroll
        for (int e = 0; e < 4; e++)
            if (val[e]) sk[hist2[kcs[e]] + olds[e]] = keys[e];
        __syncthreads();
        // ---- per-slot tie fix-up: insertion sort slots with >=2 (rare) ----
        #pragma unroll
        for (int e = 0; e < 4; e++) {
            if (val[e] && olds[e] == 0) {
                uint32_t base = hist2[kcs[e]];
                uint32_t nxt  = (kcs[e] < 2047u) ? hist2[kcs[e] + 1] : ncand;
                if (nxt - base >= 2u) {
                    for (uint32_t a2 = base + 1; a2 < nxt; a2++) {
                        ull kv = sk[a2];
                        uint32_t b2 = a2;
                        while (b2 > base && sk[b2 - 1] > kv) { sk[b2] = sk[b2 - 1]; b2--; }
                        sk[b2] = kv;
                    }
                }
            }
        }
    } else {
        // ================= bitonic fallback (R11 code, unchanged) =================
        uint32_t nsort = 1024;
        while (nsort < ncand) nsort <<= 1;            // 1024 / 2048 / 4096 (uniform)
        if (nsort <= 2048) {
            const int TS2 = (int)(nsort >> 1);
            ull E0 = ~0ull, E1 = ~0ull;
            if (t < TS2) {
                int e = 2 * t;
                E0 = (e < (int)ncand)     ? list[e]     : ~0ull;
                E1 = (e + 1 < (int)ncand) ? list[e + 1] : ~0ull;
            }
            for (uint32_t k = 2; k <= nsort; k <<= 1) {
                for (uint32_t j = k >> 1; j > 0; j >>= 1) {
                    if (j >= 128) {
                        __syncthreads();
                        if (t < TS2) {
                            ulonglong2 wv; wv.x = E0; wv.y = E1;
                            *(ulonglong2*)&sk[2 * t] = wv;
                        }
                        __syncthreads();
                        if (t < TS2) {
                            uint32_t e0 = 2 * t;
                            ulonglong2 rv = *(const ulonglong2*)&sk[e0 ^ j];
                            bool km = (((e0 & k) == 0) != ((e0 & j) == 0));
                            E0 = ((E0 > rv.x) == km) ? E0 : rv.x;
                            E1 = ((E1 > rv.y) == km) ? E1 : rv.y;
                        }
                    } else if (t < TS2) {
                        if (j >= 2) {
                            int d = (int)(j >> 1);
                            bool km = ((((2 * t) & k) == 0) != (((2 * t) & j) == 0));
                            ull o0 = __shfl_xor(E0, d);
                            ull o1 = __shfl_xor(E1, d);
                            E0 = ((E0 > o0) == km) ? E0 : o0;
                            E1 = ((E1 > o1) == km) ? E1 : o1;
                        } else {
                            bool up = (((2 * t) & k) == 0);
                            cmpsw(E0, E1, up);
                        }
                    }
                }
            }
            __syncthreads();
            if (t < TS2) {
                ulonglong2 wv; wv.x = E0; wv.y = E1;
                *(ulonglong2*)&sk[2 * t] = wv;
            }
        } else {
            const int TS = (int)(nsort >> 2);
            ull E[4];
            if (t < TS) {
                #pragma unroll
                for (int rr = 0; rr < 4; rr++) {
                    int e = 4 * t + rr;
                    E[rr] = (e < (int)ncand) ? list[e] : ~0ull;
                }
            }
            for (uint32_t k = 2; k <= nsort; k <<= 1) {
                for (uint32_t j = k >> 1; j > 0; j >>= 1) {
                    if (j >= 256) {
                        __syncthreads();
                        if (t < TS) {
                            #pragma unroll
                            for (int rr = 0; rr < 4; rr++) sk[SKEW(4 * t + rr)] = E[rr];
                        }
                        __syncthreads();
                        if (t < TS) {
                            #pragma unroll
                            for (int rr = 0; rr < 4; rr++) {
                                uint32_t e = 4 * t + rr;
                                ull o = sk[SKEW(e ^ j)];
                                bool keepMax = (((e & k) == 0) != ((e & j) == 0));
                                bool gt = E[rr] > o;
                                E[rr] = (gt == keepMax) ? E[rr] : o;
                            }
                        }
                    } else if (t < TS) {
                        if (j >= 4) {
                            int d = (int)(j >> 2);
                            #pragma unroll
                            for (int rr = 0; rr < 4; rr++) {
                                uint32_t e = 4 * t + rr;
                                ull o = __shfl_xor(E[rr], d);
                                bool keepMax = (((e & k) == 0) != ((e & j) == 0));
                                bool gt = E[rr] > o;
                                E[rr] = (gt == keepMax) ? E[rr] : o;
                            }
                        } else if (j == 2) {
                            bool up = (((4 * t) & k) == 0);
                            cmpsw(E[0], E[2], up); cmpsw(E[1], E[3], up);
                        } else {
                            bool upA = (((4 * t) & k) == 0);
                            bool upB = (((4 * t + 2) & k) == 0);
                            cmpsw(E[0], E[1], upA);
                            cmpsw(E[2], E[3], upB);
                        }
                    }
                }
            }
            __syncthreads();
            if (t < TS) {
                #pragma unroll
                for (int rr = 0; rr < 4; rr++) sk[SKEW(4 * t + rr)] = E[rr];
            }
        }
    }
    __syncthreads();
    ull skey;
    if (ctOK) skey = sk[t];
    else {
        uint32_t nsort = 1024;
        while (nsort < ncand) nsort <<= 1;
        skey = (nsort <= 2048) ? sk[t] : sk[SKEW(t)];
    }
    __syncthreads();                                  // sk region free for reuse

    // ---- extract + gather + prep (exact reference fp32 order; max is associative) ----
    float4 bx = make_float4(0.f, 0.f, 0.f, 0.f);
    float cf = 0.f, lb = 0.f;
    uint32_t lab = 0;
    if ((uint32_t)t < nsel) {
        uint32_t idx = (uint32_t)(skey >> 7) & 0x3FFFFu;
        lab = (uint32_t)skey & 127u;
        cf = __uint_as_float(0x3F000000u + (0x1000000u - (uint32_t)(skey >> 25)));
        lb = (float)lab;
        bx = bboxes[idx];
    }
    float m = fmaxf(fmaxf(bx.x, bx.y), fmaxf(bx.z, bx.w));
    for (int d = 32; d > 0; d >>= 1) m = fmaxf(m, __shfl_xor(m, d));
    if ((t & 63) == 0) red16[t >> 6] = m;
    __syncthreads();
    float M = red16[0];
    #pragma unroll
    for (int w = 1; w < 16; w++) M = fmaxf(M, red16[w]);
    M = __fadd_rn(M, 1.0f);
    float o = __fmul_rn(lb, M);
    float4 q;
    q.x = __fadd_rn(bx.x, o); q.y = __fadd_rn(bx.y, o);
    q.z = __fadd_rn(bx.z, o); q.w = __fadd_rn(bx.w, o);
    ob[t] = q;
    ar[t] = __fmul_rn(__fsub_rn(q.z, q.x), __fsub_rn(q.w, q.y));
    g[t] = 0xFFFFFFFFu;                               // scatter target, init invalid
    if (t < N_CLS) ovr[t] = 0;
    keepA[t] = 0;
    if (t < 640) {                                    // zero cmask[80][16] (1280 u64)
        ulonglong2 z; z.x = 0; z.y = 0;
        *(ulonglong2*)&cmask[2 * t] = z;
    }
    __syncthreads();

    // ---- popcount-rank class grouping ----
    // g := stable partition by class of the rank-sorted sequence; bit-identical
    // to sorting (lab<<10|t) ascending.
    if ((uint32_t)t < nsel)
        atomicOr(&cmask[lab * 16 + (t >> 6)], 1ull << (t & 63));
    __syncthreads();
    if (t < N_CLS) {                                  // per-class counts
        uint32_t s = 0;
        #pragma unroll
        for (int w = 0; w < 16; w++) s += (uint32_t)__popcll(cmask[t * 16 + w]);
        cnt[t] = s;
    }
    __syncthreads();
    if (t < N_CLS) {                                  // exclusive prefix (starts)
        uint32_t s = 0;
        for (int i = 0; i < N_CLS - 1; i++) {
            uint32_t v = cnt[i];                      // broadcast read
            if (i < t) s += v;
        }
        stt[t] = s;
    }
    __syncthreads();
    if ((uint32_t)t < nsel) {                         // within-class rank + scatter
        const ull* cm = &cmask[lab * 16];
        uint32_t w = (uint32_t)t >> 6;
        uint32_t r = (uint32_t)__popcll(cm[w] & ((1ull << (t & 63)) - 1ull));
        for (uint32_t ww = 0; ww < w; ww++) r += (uint32_t)__popcll(cm[ww]);
        g[stt[lab] + r] = (lab << 10) | (uint32_t)t;
    }
    __syncthreads();

    // ---- parallel suppression bitmask: sup[p] bit (q-p-1) = iou(p,q)>thr, same class ----
    uint32_t gp = g[t];
    {
        ull sp = 0;
        if (gp != 0xFFFFFFFFu) {
            uint32_t labi = gp >> 10;
            uint32_t ri = gp & 1023u;
            float4 oi = ob[ri]; float ai = ar[ri];
            for (int qq = t + 1; qq < 1024; qq++) {
                uint32_t gq = g[qq];
                if ((gq >> 10) != labi) break;
                int dq = qq - t;
                if (dq > 64) { ovr[labi] = 1; break; }
                uint32_t rj = gq & 1023u;
                float4 oj = ob[rj];
                float lx = fmaxf(oi.x, oj.x), ly = fmaxf(oi.y, oj.y);
                float rx = fminf(oi.z, oj.z), ry = fminf(oi.w, oj.w);
                float wx = fmaxf(__fsub_rn(rx, lx), 0.f);
                float wy = fmaxf(__fsub_rn(ry, ly), 0.f);
                float inter = __fmul_rn(wx, wy);
                float uni = __fsub_rn(__fadd_rn(ai, ar[rj]), inter);
                float iou = __fdiv_rn(inter, fmaxf(uni, 1e-9f));
                if (iou > 0.6f) sp |= 1ull << (dq - 1);
            }
        }
        sup[t] = sp;
    }
    __syncthreads();

    // ---- 80-lane register greedy (rank order within class = score order) ----
    if (t < N_CLS) {
        uint32_t n = cnt[t];
        if (n > 0) {
            uint32_t s0 = stt[t];
            if (n <= 64 && !ovr[t]) {
                ull kill = 0;
                for (uint32_t i = 0; i < n; i++) {
                    if (!((kill >> i) & 1ull)) {
                        if (i + 1 < 64) kill |= sup[s0 + i] << (i + 1);
                        keepA[g[s0 + i] & 1023u] = 1;
                    }
                }
            } else {                                  // oversized class: serial fallback
                for (uint32_t i = 0; i < n; i++) {
                    uint32_t ri = g[s0 + i] & 1023u;
                    float4 oi = ob[ri]; float ai = ar[ri];
                    bool kp = true;
                    for (uint32_t m2 = 0; m2 < i && kp; m2++) {
                        uint32_t rm = g[s0 + m2] & 1023u;
                        if (!keepA[rm]) continue;
                        float4 om = ob[rm];
                        float lx = fmaxf(om.x, oi.x), ly = fmaxf(om.y, oi.y);
                        float rx = fminf(om.z, oi.z), ry = fminf(om.w, oi.w);
                        float wx = fmaxf(__fsub_rn(rx, lx), 0.f);
                        float wy = fmaxf(__fsub_rn(ry, ly), 0.f);
                        float inter = __fmul_rn(wx, wy);
                        float uni = __fsub_rn(__fadd_rn(ar[rm], ai), inter);
                        float iou = __fdiv_rn(inter, fmaxf(uni, 1e-9f));
                        if (iou > 0.6f) kp = false;
                    }
                    keepA[ri] = kp ? 1 : 0;
                }
            }
        }
    }
    __syncthreads();

    // ---- masked fp32 output ----
    const bool keep = keepA[t] != 0;
    float v0 = keep ? bx.x : 0.f, v1 = keep ? bx.y : 0.f;
    float v2 = keep ? bx.z : 0.f, v3 = keep ? bx.w : 0.f;
    float v4 = keep ? cf : 0.f, v5 = keep ? lb : 0.f;
    float2* o2 = (float2*)out;
    o2[t * 3 + 0] = make_float2(v0, v1);
    o2[t * 3 + 1] = make_float2(v2, v3);
    o2[t * 3 + 2] = make_float2(v4, v5);
}

extern "C" void kernel_launch(void* const* d_in, const int* in_sizes, int n_in,
                              void* d_out, int out_size, void* d_ws, size_t ws_size,
                              hipStream_t stream) {
    const float* bboxes = (const float*)d_in[0];
    const float* scores = (const float*)d_in[1];
    if (n_in >= 2 && in_sizes[0] > in_sizes[1]) {   // defensive: scores is the 20x larger input
        bboxes = (const float*)d_in[1];
        scores = (const float*)d_in[0];
    }

    if (ws_size < (size_t)WS_REQUIRED) {
        k_sentinel<<<(K_TOP * 6 + 255) / 256, 256, 0, stream>>>(
            (float*)d_out, (float)(ws_size >> 10));
        return;
    }

    char* ws = (char*)d_ws;
    uint32_t* hist   = (uint32_t*)(ws + OFF_HIST);
    uint32_t* ctrl   = (uint32_t*)(ws + OFF_CTRL);
    uint16_t* bins16 = (uint16_t*)(ws + OFF_BINS);
    ull*      list   = (ull*)(ws + OFF_LIST);

    hipMemsetAsync(ws, 0, MEMSET_BYTES, stream);    // hist + ctrl
    k_conf  <<<N_ANCH / 128, 256, 0, stream>>>(scores, bins16, hist);
    k_cut   <<<1,           1024, 0, stream>>>(hist, ctrl);
    k_gather<<<256,          256, 0, stream>>>(scores, bins16, ctrl, list);
    k_final <<<1,           1024, 0, stream>>>((const float4*)bboxes, ctrl, list,
                                               (float*)d_out);
}

// Round 5
// 177.185 us; speedup vs baseline: 1.5400x; 1.0241x over previous
//
#include <hip/hip_runtime.h>
#include <stdint.h>

// YoloNAS postprocess, fp32 in/out — R13.
// memset | k_conf (2048 blk): conf/argmax -> bins16 + SWIZZLED 32k hist (depth-4 MLP ring)
//        | k_gather (64 blk x 1024 thr): INLINED register-held cutoff (was k_cut)
//          + candidate emit (block-aggregated)
//        | k_final (1 blk): counting-rank sort (bitonic fallback) -> popcount-rank
//          class grouping -> GROUPED-ORDER suppression (obg/arg materialized once,
//          delta loop, no dependent indirection) -> 80-lane greedy -> output
// R13 changes vs R12 (keys, predicates, fp32 NMS math identical; absmax 0):
//  (1) k_cut merged into k_gather (64x1024): fast reg-held cutoff run per block
//      (~1us redundant L2 reads) -> 5 dispatches -> 4, dependency gap gone.
//  (2) k_final suppression: obg[i]=ob[g[i]&1023] materialized once; trip count
//      from cnt/stt; loop reads obg[t+d] (address-predictable, unrolled) instead
//      of g[qq]->ob[g[qq]] dependent LDS chain (~120cyc x 2 x 64 per thread).
//  (3) ovr flag deleted: provably redundant (set requires n>=66; bitmask path
//      already requires n<=64). Suppression bits + greedy order bit-identical.

#define N_ANCH   262144
#define N_CLS    80
#define K_TOP    1024
#define CAP      4096

typedef unsigned long long ull;

// hist layout bijection: bit-rotate 15-bit bin, b = [b14..b11 | b10..b0]
// -> slot = [b10..b0 | b14..b11]. Value-adjacent bins land 16 u32 (64B) apart.
#define HSLOT(b) ((((b) & 2047u) << 4) | ((b) >> 11))
// skewed LDS index for the u64 sort scratch (bitonic 4096 path only)
#define SKEW(e) ((uint32_t)(e) + ((uint32_t)(e) >> 4))

// ---- workspace layout (bytes); total 688192 < proven ws_size >= 733248 ----
#define OFF_HIST  0           // u32[32768] (swizzled layout)
#define OFF_CTRL  131072      // u32[16]: [0]=cand counter, [1]=nsel
#define MEMSET_BYTES 131136
#define OFF_BINS  131136      // u16[262144]: valid?0x8000|bin:0
#define OFF_LIST  655424      // u64[4096] candidate keys
#define WS_REQUIRED 688192

__global__ __launch_bounds__(256) void k_sentinel(float* __restrict__ out, float v) {
    int i = blockIdx.x * 256 + threadIdx.x;
    if (i < K_TOP * 6) out[i] = v;
}

static __device__ __forceinline__ uint32_t conf_key24(float best) {
    uint32_t u = __float_as_uint(best);
    if (u > 0x3F800000u) u = 0x3F800000u;    // defensive; conf in [0.5, 1]
    if (u < 0x3F000000u) u = 0x3F000000u;
    return u - 0x3F000000u;                  // 0..0x800000, monotone in conf
}

static __device__ __forceinline__ void cmpsw(ull& x, ull& y, bool up) {
    ull mn = x < y ? x : y, mx = x < y ? y : x;
    x = up ? mn : mx; y = up ? mx : mn;
}

// ---------- kernel 1: conf/argmax, 16 lanes/anchor, 128 anchors/block ----------
__global__ __launch_bounds__(256) void k_conf(const float* __restrict__ scores,
                                              uint16_t* __restrict__ bins16,
                                              uint32_t* __restrict__ hist) {
    const int t = threadIdx.x;
    const int r = t >> 4, s = t & 15;
    const int a0 = blockIdx.x * 128 + r;
    const float* base = scores + (size_t)a0 * N_CLS;
    // depth-4 software pipeline: 8 (v0) + 2 (v1, s<4) loads in flight per lane group
    float4 v0[4], v1[4];
    #pragma unroll
    for (int p = 0; p < 4; p++) {
        const float* nb = base + (size_t)p * 16 * N_CLS;
        v0[p] = ((const float4*)nb)[s];
        if (s < 4) v1[p] = ((const float4*)nb)[16 + s];
    }
    #pragma unroll
    for (int i = 0; i < 8; i++) {
        float4 c0 = v0[i & 3], c1 = v1[i & 3];
        if (i + 4 < 8) {                              // refill ring 4 tiles ahead
            const float* nb = base + (size_t)(i + 4) * 16 * N_CLS;
            v0[i & 3] = ((const float4*)nb)[s];
            if (s < 4) v1[i & 3] = ((const float4*)nb)[16 + s];
        }
        float best = c0.x; int lab = 4 * s;           // first-max (strict >)
        if (c0.y > best) { best = c0.y; lab = 4 * s + 1; }
        if (c0.z > best) { best = c0.z; lab = 4 * s + 2; }
        if (c0.w > best) { best = c0.w; lab = 4 * s + 3; }
        if (s < 4) {
            const int c = 64 + 4 * s;
            if (c1.x > best) { best = c1.x; lab = c; }
            if (c1.y > best) { best = c1.y; lab = c + 1; }
            if (c1.z > best) { best = c1.z; lab = c + 2; }
            if (c1.w > best) { best = c1.w; lab = c + 3; }
        }
        ull key = ((ull)(uint32_t)__float_as_uint(best) << 7) | (ull)(uint32_t)(127 - lab);
        ull o;
        o = __shfl_xor(key, 1); if (o > key) key = o;
        o = __shfl_xor(key, 2); if (o > key) key = o;
        o = __shfl_xor(key, 4); if (o > key) key = o;
        o = __shfl_xor(key, 8); if (o > key) key = o;
        if (s == 0) {
            const int a = a0 + i * 16;
            float bv = __uint_as_float((uint32_t)(key >> 7));
            uint16_t pk = 0;
            if (bv >= 0.5f) {
                uint32_t bin = conf_key24(bv) >> 8;
                if (bin > 32767u) bin = 32767u;
                atomicAdd(&hist[HSLOT(bin)], 1u);     // swizzled slot, linear bin number
                pk = (uint16_t)(0x8000u | bin);
            }
            bins16[a] = pk;
        }
    }
}

// ---------- kernel 2: cutoff (per-block, reg-held) + candidate emit ----------
// 64 blocks x 1024 threads, 4 anchors/thread. Cutoff logic = old k_cut, run
// redundantly per block (~1us of L2-resident hist reads) -> no k_cut launch.
__global__ __launch_bounds__(1024) void k_gather(const float* __restrict__ scores,
                                                 const uint16_t* __restrict__ bins16,
                                                 const uint32_t* __restrict__ hist,
                                                 uint32_t* __restrict__ ctrl,
                                                 ull* __restrict__ list) {
    __shared__ uint32_t wtot[16], wsuf[16], shCT, lcnt, lbase;
    const int t = threadIdx.x, b = blockIdx.x;
    const int lane = t & 63, w = t >> 6;
    if (t == 0) { shCT = 0; lcnt = 0; lbase = 0; }
    // ---- cutoff: thread t owns bins [32t, 32t+32) in registers ----
    // bins b15 = 32t + i: slot = ((t&63)<<9) | (i<<4) | (t>>6)
    const uint32_t sbase = (((uint32_t)t & 63u) << 9) | ((uint32_t)t >> 6);
    uint32_t c[32];
    #pragma unroll
    for (int i = 0; i < 32; i++) c[i] = hist[sbase | ((uint32_t)i << 4)];
    uint32_t part = 0;
    #pragma unroll
    for (int i = 0; i < 32; i++) part += c[i];
    uint32_t x = part;                                // wave inclusive suffix scan
    #pragma unroll
    for (int d = 1; d < 64; d <<= 1) {
        uint32_t o = __shfl_down(x, d);
        if (lane + d < 64) x += o;
    }
    if (lane == 0) wtot[w] = x;
    __syncthreads();
    if (t < 16) {
        uint32_t s = 0;
        for (int ww = t + 1; ww < 16; ww++) s += wtot[ww];
        wsuf[t] = s;                                  // waves strictly above
        if (t == 0 && b == 0) {
            uint32_t total = s + wtot[0];
            ctrl[1] = (total < K_TOP) ? total : K_TOP;   // nsel (written once)
        }
    }
    __syncthreads();
    {
        uint32_t run = (x + wsuf[w]) - part;          // count strictly above my segment
        if (run < K_TOP && run + part >= K_TOP) {     // unique crossing thread
            uint32_t fnd = 0, cbv = 0;
            #pragma unroll
            for (int i = 31; i >= 0; i--) {           // descending bins, register scan
                if (!fnd && run + c[i] >= K_TOP) { cbv = (uint32_t)(t * 32 + i); fnd = 1; }
                if (!fnd) run += c[i];
            }
            shCT = cbv;
        }
        // total < K_TOP: no writer; shCT stays 0 -> include everything
    }
    __syncthreads();
    const uint32_t cT = shCT;

    // ---- scan my 4-anchor slice, re-derive exact keys for hits ----
    const int a4 = b * 1024 + t;
    ushort4 pk4 = ((const ushort4*)bins16)[a4];
    uint16_t pk[4] = {pk4.x, pk4.y, pk4.z, pk4.w};
    ull      hk[4];                                   // keys  (compile-time indexed)
    uint32_t hs[4];                                   // local slots
    bool     hv[4];                                   // valid
    #pragma unroll
    for (int e = 0; e < 4; e++) {
        hv[e] = false; hk[e] = 0; hs[e] = 0;
        uint32_t u = pk[e];
        if ((u & 0x8000u) && (u & 0x7FFFu) >= cT) {
            const uint32_t a = (uint32_t)a4 * 4u + (uint32_t)e;
            const float4* row = (const float4*)(scores + (size_t)a * N_CLS);
            float best = -1.f; int lab = 0;
            for (int f = 0; f < 20; f++) {
                float4 w2 = row[f];
                if (w2.x > best) { best = w2.x; lab = 4 * f; }
                if (w2.y > best) { best = w2.y; lab = 4 * f + 1; }
                if (w2.z > best) { best = w2.z; lab = 4 * f + 2; }
                if (w2.w > best) { best = w2.w; lab = 4 * f + 3; }
            }
            if (best >= 0.5f) {
                uint32_t k24 = conf_key24(best);
                hk[e] = ((ull)(0x1000000u - k24) << 25) | ((ull)a << 7)
                      | (ull)(uint32_t)lab;           // ascending = conf desc, idx asc
                hs[e] = atomicAdd(&lcnt, 1u);         // LDS: ~20 hits/block
                hv[e] = true;
            }
        }
    }
    __syncthreads();
    if (t == 0 && lcnt) lbase = atomicAdd(&ctrl[0], lcnt);  // ONE global atomic/block
    __syncthreads();
    const uint32_t base2 = lbase;
    #pragma unroll
    for (int e = 0; e < 4; e++) {
        if (hv[e]) {
            uint32_t slot = base2 + hs[e];
            if (slot < CAP) list[slot] = hk[e];       // list order irrelevant: k_final sorts
        }
    }
}

// ---------- kernel 3: sort + group + grouped-order NMS + output (1 block) ----------
// LDS (sort phase): sk u64[4352]@0 (34816B) | hist2 u32[2048]@34816 | gfail@43008 |
//   wtot2[16]@43012 | wbase[16]@43076
// LDS (post-sort, sequential reuse): ob f4[1024]@0 | obg f4[1024]@16384 |
//   ar f[1024]@32768 | arg f[1024]@36864 | red16 f[16]@40960 | g u32[1024]@41024 |
//   sup u64[1024]@45120 | keepA u8[1024]@53312 | cnt u32[80]@54336 |
//   stt u32[80]@54656 | cmask u64[80][16]@54976 (ends 65216)
__global__ __launch_bounds__(1024) void k_final(const float4* __restrict__ bboxes,
                                                const uint32_t* __restrict__ ctrl,
                                                const ull* __restrict__ list,
                                                float* __restrict__ out) {
    __shared__ __align__(16) char smem[65280];
    ull*      sk    = (ull*)smem;
    float4*   ob    = (float4*)smem;
    float4*   obg   = (float4*)(smem + 16384);
    float*    ar    = (float*)(smem + 32768);
    float*    arg   = (float*)(smem + 36864);
    float*    red16 = (float*)(smem + 40960);
    uint32_t* g     = (uint32_t*)(smem + 41024);
    ull*      sup   = (ull*)(smem + 45120);
    uint8_t*  keepA = (uint8_t*)(smem + 53312);
    uint32_t* cnt   = (uint32_t*)(smem + 54336);
    uint32_t* stt   = (uint32_t*)(smem + 54656);
    ull*      cmask = (ull*)(smem + 54976);           // [80][16] bit t = rank t present
    uint32_t* hist2 = (uint32_t*)(smem + 34816);      // sort phase only
    uint32_t* gfail = (uint32_t*)(smem + 43008);
    uint32_t* wtot2 = (uint32_t*)(smem + 43012);
    uint32_t* wbase = (uint32_t*)(smem + 43076);
    const int t = threadIdx.x;
    const uint32_t nsel = ctrl[1];
    uint32_t ncand = ctrl[0]; if (ncand > CAP) ncand = CAP;

    // ================= counting-rank sort (fast path) =================
    // Candidate keys: k24c = (key>>25)-0x800000 expected < ~1100 (cutoff ~4 fine
    // bins below top). Rank = #smaller (k24c, anchor).
    ((uint2*)hist2)[t] = make_uint2(0u, 0u);          // zero 2048 slots
    if (t == 0) *gfail = 0;
    __syncthreads();
    ull      keys[4]; uint32_t kcs[4], olds[4]; bool val[4];
    #pragma unroll
    for (int e = 0; e < 4; e++) {
        int i = t + 1024 * e;
        val[e] = (i < (int)ncand); keys[e] = 0; kcs[e] = 0; olds[e] = 0;
        if (val[e]) {
            ull kk = list[i];
            keys[e] = kk;
            uint32_t kc = (uint32_t)(kk >> 25) - 0x800000u;
            if (kc >= 2048u) { *gfail = 1; val[e] = false; }
            else {
                kcs[e] = kc;
                uint32_t od = atomicAdd(&hist2[kc], 1u);
                olds[e] = od;
                if (od >= 16u) *gfail = 1;            // slot too deep: fallback
            }
        }
    }
    __syncthreads();
    const bool ctOK = (*gfail == 0);                  // uniform across block

    if (ctOK) {
        // ---- exclusive prefix over 2048 slots (2/thread, wave scan) ----
        uint32_t v0h = hist2[2 * t], v1h = hist2[2 * t + 1];
        uint32_t sseg = v0h + v1h;
        uint32_t incl = sseg;
        const int lane = t & 63, w = t >> 6;
        #pragma unroll
        for (int d = 1; d < 64; d <<= 1) {
            uint32_t o = __shfl_up(incl, d);
            if (lane >= d) incl += o;
        }
        if (lane == 63) wtot2[w] = incl;
        __syncthreads();
        if (t < 16) {
            uint32_t sb = 0;
            for (int i = 0; i < 16; i++) { uint32_t v = wtot2[i]; if (i < t) sb += v; }
            wbase[t] = sb;
        }
        __syncthreads();
        uint32_t ex = wbase[w] + incl - sseg;         // exclusive before slot 2t
        hist2[2 * t]     = ex;
        hist2[2 * t + 1] = ex + v0h;
        __syncthreads();
        // ---- scatter to rank (arrival order within slot) ----
        #pragma unroll
        for (int e = 0; e < 4; e++)
            if (val[e]) sk[hist2[kcs[e]] + olds[e]] = keys[e];
        __syncthreads();
        // ---- per-slot tie fix-up: insertion sort slots with >=2 (rare) ----
        #pragma unroll
        for (int e = 0; e < 4; e++) {
            if (val[e] && olds[e] == 0) {
                uint32_t base = hist2[kcs[e]];
                uint32_t nxt  = (kcs[e] < 2047u) ? hist2[kcs[e] + 1] : ncand;
                if (nxt - base >= 2u) {
                    for (uint32_t a2 = base + 1; a2 < nxt; a2++) {
                        ull kv = sk[a2];
                        uint32_t b2 = a2;
                        while (b2 > base && sk[b2 - 1] > kv) { sk[b2] = sk[b2 - 1]; b2--; }
                        sk[b2] = kv;
                    }
                }
            }
        }
    } else {
        // ================= bitonic fallback (R11 code, unchanged) =================
        uint32_t nsort = 1024;
        while (nsort < ncand) nsort <<= 1;            // 1024 / 2048 / 4096 (uniform)
        if (nsort <= 2048) {
            const int TS2 = (int)(nsort >> 1);
            ull E0 = ~0ull, E1 = ~0ull;
            if (t < TS2) {
                int e = 2 * t;
                E0 = (e < (int)ncand)     ? list[e]     : ~0ull;
                E1 = (e + 1 < (int)ncand) ? list[e + 1] : ~0ull;
            }
            for (uint32_t k = 2; k <= nsort; k <<= 1) {
                for (uint32_t j = k >> 1; j > 0; j >>= 1) {
                    if (j >= 128) {
                        __syncthreads();
                        if (t < TS2) {
                            ulonglong2 wv; wv.x = E0; wv.y = E1;
                            *(ulonglong2*)&sk[2 * t] = wv;
                        }
                        __syncthreads();
                        if (t < TS2) {
                            uint32_t e0 = 2 * t;
                            ulonglong2 rv = *(const ulonglong2*)&sk[e0 ^ j];
                            bool km = (((e0 & k) == 0) != ((e0 & j) == 0));
                            E0 = ((E0 > rv.x) == km) ? E0 : rv.x;
                            E1 = ((E1 > rv.y) == km) ? E1 : rv.y;
                        }
                    } else if (t < TS2) {
                        if (j >= 2) {
                            int d = (int)(j >> 1);
                            bool km = ((((2 * t) & k) == 0) != (((2 * t) & j) == 0));
                            ull o0 = __shfl_xor(E0, d);
                            ull o1 = __shfl_xor(E1, d);
                            E0 = ((E0 > o0) == km) ? E0 : o0;
                            E1 = ((E1 > o1) == km) ? E1 : o1;
                        } else {
                            bool up = (((2 * t) & k) == 0);
                            cmpsw(E0, E1, up);
                        }
                    }
                }
            }
            __syncthreads();
            if (t < TS2) {
                ulonglong2 wv; wv.x = E0; wv.y = E1;
                *(ulonglong2*)&sk[2 * t] = wv;
            }
        } else {
            const int TS = (int)(nsort >> 2);
            ull E[4];
            if (t < TS) {
                #pragma unroll
                for (int rr = 0; rr < 4; rr++) {
                    int e = 4 * t + rr;
                    E[rr] = (e < (int)ncand) ? list[e] : ~0ull;
                }
            }
            for (uint32_t k = 2; k <= nsort; k <<= 1) {
                for (uint32_t j = k >> 1; j > 0; j >>= 1) {
                    if (j >= 256) {
                        __syncthreads();
                        if (t < TS) {
                            #pragma unroll
                            for (int rr = 0; rr < 4; rr++) sk[SKEW(4 * t + rr)] = E[rr];
                        }
                        __syncthreads();
                        if (t < TS) {
                            #pragma unroll
                            for (int rr = 0; rr < 4; rr++) {
                                uint32_t e = 4 * t + rr;
                                ull o = sk[SKEW(e ^ j)];
                                bool keepMax = (((e & k) == 0) != ((e & j) == 0));
                                bool gt = E[rr] > o;
                                E[rr] = (gt == keepMax) ? E[rr] : o;
                            }
                        }
                    } else if (t < TS) {
                        if (j >= 4) {
                            int d = (int)(j >> 2);
                            #pragma unroll
                            for (int rr = 0; rr < 4; rr++) {
                                uint32_t e = 4 * t + rr;
                                ull o = __shfl_xor(E[rr], d);
                                bool keepMax = (((e & k) == 0) != ((e & j) == 0));
                                bool gt = E[rr] > o;
                                E[rr] = (gt == keepMax) ? E[rr] : o;
                            }
                        } else if (j == 2) {
                            bool up = (((4 * t) & k) == 0);
                            cmpsw(E[0], E[2], up); cmpsw(E[1], E[3], up);
                        } else {
                            bool upA = (((4 * t) & k) == 0);
                            bool upB = (((4 * t + 2) & k) == 0);
                            cmpsw(E[0], E[1], upA);
                            cmpsw(E[2], E[3], upB);
                        }
                    }
                }
            }
            __syncthreads();
            if (t < TS) {
                #pragma unroll
                for (int rr = 0; rr < 4; rr++) sk[SKEW(4 * t + rr)] = E[rr];
            }
        }
    }
    __syncthreads();
    ull skey;
    if (ctOK) skey = sk[t];
    else {
        uint32_t nsort = 1024;
        while (nsort < ncand) nsort <<= 1;
        skey = (nsort <= 2048) ? sk[t] : sk[SKEW(t)];
    }
    __syncthreads();                                  // sk region free for reuse

    // ---- extract + gather + prep (exact reference fp32 order; max is associative) ----
    float4 bx = make_float4(0.f, 0.f, 0.f, 0.f);
    float cf = 0.f, lb = 0.f;
    uint32_t lab = 0;
    if ((uint32_t)t < nsel) {
        uint32_t idx = (uint32_t)(skey >> 7) & 0x3FFFFu;
        lab = (uint32_t)skey & 127u;
        cf = __uint_as_float(0x3F000000u + (0x1000000u - (uint32_t)(skey >> 25)));
        lb = (float)lab;
        bx = bboxes[idx];
    }
    float m = fmaxf(fmaxf(bx.x, bx.y), fmaxf(bx.z, bx.w));
    for (int d = 32; d > 0; d >>= 1) m = fmaxf(m, __shfl_xor(m, d));
    if ((t & 63) == 0) red16[t >> 6] = m;
    __syncthreads();
    float M = red16[0];
    #pragma unroll
    for (int w = 1; w < 16; w++) M = fmaxf(M, red16[w]);
    M = __fadd_rn(M, 1.0f);
    float o = __fmul_rn(lb, M);
    float4 q;
    q.x = __fadd_rn(bx.x, o); q.y = __fadd_rn(bx.y, o);
    q.z = __fadd_rn(bx.z, o); q.w = __fadd_rn(bx.w, o);
    ob[t] = q;
    ar[t] = __fmul_rn(__fsub_rn(q.z, q.x), __fsub_rn(q.w, q.y));
    g[t] = 0xFFFFFFFFu;                               // scatter target, init invalid
    keepA[t] = 0;
    if (t < 640) {                                    // zero cmask[80][16] (1280 u64)
        ulonglong2 z; z.x = 0; z.y = 0;
        *(ulonglong2*)&cmask[2 * t] = z;
    }
    __syncthreads();

    // ---- popcount-rank class grouping ----
    // g := stable partition by class of the rank-sorted sequence; bit-identical
    // to sorting (lab<<10|t) ascending.
    if ((uint32_t)t < nsel)
        atomicOr(&cmask[lab * 16 + (t >> 6)], 1ull << (t & 63));
    __syncthreads();
    if (t < N_CLS) {                                  // per-class counts
        uint32_t s = 0;
        #pragma unroll
        for (int w = 0; w < 16; w++) s += (uint32_t)__popcll(cmask[t * 16 + w]);
        cnt[t] = s;
    }
    __syncthreads();
    if (t < N_CLS) {                                  // exclusive prefix (starts)
        uint32_t s = 0;
        for (int i = 0; i < N_CLS - 1; i++) {
            uint32_t v = cnt[i];                      // broadcast read
            if (i < t) s += v;
        }
        stt[t] = s;
    }
    __syncthreads();
    if ((uint32_t)t < nsel) {                         // within-class rank + scatter
        const ull* cm = &cmask[lab * 16];
        uint32_t w = (uint32_t)t >> 6;
        uint32_t r = (uint32_t)__popcll(cm[w] & ((1ull << (t & 63)) - 1ull));
        for (uint32_t ww = 0; ww < w; ww++) r += (uint32_t)__popcll(cm[ww]);
        g[stt[lab] + r] = (lab << 10) | (uint32_t)t;
    }
    __syncthreads();

    // ---- materialize boxes/areas in GROUPED order (one indirection, once) ----
    uint32_t gp = g[t];
    if (gp != 0xFFFFFFFFu) {
        uint32_t ri = gp & 1023u;
        obg[t] = ob[ri];
        arg[t] = ar[ri];
    }
    __syncthreads();

    // ---- suppression bitmask: delta loop, address-predictable LDS reads ----
    {
        ull sp = 0;
        if (gp != 0xFFFFFFFFu) {
            uint32_t labi = gp >> 10;
            uint32_t nsucc = cnt[labi] - (uint32_t)(t - stt[labi]) - 1u;
            uint32_t trips = nsucc > 64u ? 64u : nsucc;
            float4 oi = obg[t]; float ai = arg[t];
            #pragma unroll 4
            for (uint32_t d = 1; d <= trips; d++) {
                float4 oj = obg[t + d];
                float aj = arg[t + d];
                float lx = fmaxf(oi.x, oj.x), ly = fmaxf(oi.y, oj.y);
                float rx = fminf(oi.z, oj.z), ry = fminf(oi.w, oj.w);
                float wx = fmaxf(__fsub_rn(rx, lx), 0.f);
                float wy = fmaxf(__fsub_rn(ry, ly), 0.f);
                float inter = __fmul_rn(wx, wy);
                float uni = __fsub_rn(__fadd_rn(ai, aj), inter);
                float iou = __fdiv_rn(inter, fmaxf(uni, 1e-9f));
                if (iou > 0.6f) sp |= 1ull << (d - 1);
            }
        }
        sup[t] = sp;
    }
    __syncthreads();

    // ---- 80-lane register greedy (rank order within class = score order) ----
    if (t < N_CLS) {
        uint32_t n = cnt[t];
        if (n > 0) {
            uint32_t s0 = stt[t];
            if (n <= 64) {                            // bitmask path (ovr was redundant)
                ull kill = 0;
                for (uint32_t i = 0; i < n; i++) {
                    if (!((kill >> i) & 1ull)) {
                        if (i + 1 < 64) kill |= sup[s0 + i] << (i + 1);
                        keepA[g[s0 + i] & 1023u] = 1;
                    }
                }
            } else {                                  // oversized class: serial fallback
                for (uint32_t i = 0; i < n; i++) {
                    uint32_t ri = g[s0 + i] & 1023u;
                    float4 oi = obg[s0 + i]; float ai = arg[s0 + i];
                    bool kp = true;
                    for (uint32_t m2 = 0; m2 < i && kp; m2++) {
                        if (!keepA[g[s0 + m2] & 1023u]) continue;
                        float4 om = obg[s0 + m2];
                        float lx = fmaxf(om.x, oi.x), ly = fmaxf(om.y, oi.y);
                        float rx = fminf(om.z, oi.z), ry = fminf(om.w, oi.w);
                        float wx = fmaxf(__fsub_rn(rx, lx), 0.f);
                        float wy = fmaxf(__fsub_rn(ry, ly), 0.f);
                        float inter = __fmul_rn(wx, wy);
                        float uni = __fsub_rn(__fadd_rn(arg[s0 + m2], ai), inter);
                        float iou = __fdiv_rn(inter, fmaxf(uni, 1e-9f));
                        if (iou > 0.6f) kp = false;
                    }
                    keepA[ri] = kp ? 1 : 0;
                }
            }
        }
    }
    __syncthreads();

    // ---- masked fp32 output ----
    const bool keep = keepA[t] != 0;
    float v0 = keep ? bx.x : 0.f, v1 = keep ? bx.y : 0.f;
    float v2 = keep ? bx.z : 0.f, v3 = keep ? bx.w : 0.f;
    float v4 = keep ? cf : 0.f, v5 = keep ? lb : 0.f;
    float2* o2 = (float2*)out;
    o2[t * 3 + 0] = make_float2(v0, v1);
    o2[t * 3 + 1] = make_float2(v2, v3);
    o2[t * 3 + 2] = make_float2(v4, v5);
}

extern "C" void kernel_launch(void* const* d_in, const int* in_sizes, int n_in,
                              void* d_out, int out_size, void* d_ws, size_t ws_size,
                              hipStream_t stream) {
    const float* bboxes = (const float*)d_in[0];
    const float* scores = (const float*)d_in[1];
    if (n_in >= 2 && in_sizes[0] > in_sizes[1]) {   // defensive: scores is the 20x larger input
        bboxes = (const float*)d_in[1];
        scores = (const float*)d_in[0];
    }

    if (ws_size < (size_t)WS_REQUIRED) {
        k_sentinel<<<(K_TOP * 6 + 255) / 256, 256, 0, stream>>>(
            (float*)d_out, (float)(ws_size >> 10));
        return;
    }

    char* ws = (char*)d_ws;
    uint32_t* hist   = (uint32_t*)(ws + OFF_HIST);
    uint32_t* ctrl   = (uint32_t*)(ws + OFF_CTRL);
    uint16_t* bins16 = (uint16_t*)(ws + OFF_BINS);
    ull*      list   = (ull*)(ws + OFF_LIST);

    hipMemsetAsync(ws, 0, MEMSET_BYTES, stream);    // hist + ctrl
    k_conf  <<<N_ANCH / 128, 256, 0, stream>>>(scores, bins16, hist);
    k_gather<<<64,          1024, 0, stream>>>(scores, bins16, hist, ctrl, list);
    k_final <<<1,           1024, 0, stream>>>((const float4*)bboxes, ctrl, list,
                                               (float*)d_out);
}